// Round 1
// baseline (733.050 us; speedup 1.0000x reference)
//
#include <hip/hip_runtime.h>
#include <hip/hip_bf16.h>
#include <math.h>

#define T_TOK 2048
#define DM    1024
#define DF    4096
#define NE    8
#define BM    128
#define BN    128
#define BK    32
#define LDA   40   // LDS row stride for v1 fallback / transpose kernels only

typedef __attribute__((ext_vector_type(8))) short          bf16x8;
typedef __attribute__((ext_vector_type(8))) unsigned short ushort8;
typedef __attribute__((ext_vector_type(4))) float          f32x4;

__device__ __forceinline__ unsigned short f2bf(float f) {
  unsigned u = __builtin_bit_cast(unsigned, f);
  unsigned r = u + 0x7fffu + ((u >> 16) & 1u);   // RNE
  return (unsigned short)(r >> 16);
}

// direct global->LDS DMA, 16B per lane. LDS dest is wave-uniform base + lane*16.
__device__ __forceinline__ void gll16(const unsigned short* g, unsigned short* l) {
  __builtin_amdgcn_global_load_lds(
      (const __attribute__((address_space(1))) void*)g,
      (__attribute__((address_space(3))) void*)l, 16, 0, 0);
}

// ---------------- x f32 -> bf16 ----------------
__global__ void convert_x_kernel(const float* __restrict__ x, unsigned short* __restrict__ xb) {
  int i = blockIdx.x * blockDim.x + threadIdx.x;   // one thread per 8 elements
  const float* src = x + (size_t)i * 8;
  float4 a = *(const float4*)(src);
  float4 b = *(const float4*)(src + 4);
  ushort8 v;
  v[0] = f2bf(a.x); v[1] = f2bf(a.y); v[2] = f2bf(a.z); v[3] = f2bf(a.w);
  v[4] = f2bf(b.x); v[5] = f2bf(b.y); v[6] = f2bf(b.z); v[7] = f2bf(b.w);
  *(ushort8*)(xb + (size_t)i * 8) = v;
}

// ---------------- weight convert + transpose: W[E][K][N] f32 -> Wt[E][N][K] bf16 ----------------
template<int K, int N>
__global__ __launch_bounds__(256) void transpose_convert(
    const float* __restrict__ W, unsigned short* __restrict__ Wt)
{
  const int e  = blockIdx.z;
  const int k0 = blockIdx.y * 32;
  const int n0 = blockIdx.x * 128;
  const float* Wp = W + (size_t)e * K * N;
  unsigned short* Wo = Wt + (size_t)e * N * K;
  __shared__ float Ls[32][129];
  const int tid = threadIdx.x;
  {
    const int kl = tid >> 5;
    const int nl = (tid & 31) * 4;
#pragma unroll
    for (int p = 0; p < 4; p++) {
      const int k = kl + p * 8;
      float4 v = *(const float4*)(Wp + (size_t)(k0 + k) * N + n0 + nl);
      Ls[k][nl + 0] = v.x; Ls[k][nl + 1] = v.y; Ls[k][nl + 2] = v.z; Ls[k][nl + 3] = v.w;
    }
  }
  __syncthreads();
  {
    const int n  = tid & 127;
    const int c0 = tid >> 7;
#pragma unroll
    for (int p = 0; p < 2; p++) {
      const int c = c0 + p * 2;
      ushort8 o;
#pragma unroll
      for (int j = 0; j < 8; j++) o[j] = f2bf(Ls[c * 8 + j][n]);
      *(ushort8*)(Wo + (size_t)(n0 + n) * K + k0 + c * 8) = o;
    }
  }
}

// ---------------- gating: one wave per token ----------------
__global__ __launch_bounds__(256) void gating_kernel(
    const float* __restrict__ x, const float* __restrict__ wg, const float* __restrict__ bg,
    int* __restrict__ cnt, int* __restrict__ perm, float* __restrict__ pw)
{
  int wid  = (blockIdx.x * blockDim.x + threadIdx.x) >> 6;   // token
  int lane = threadIdx.x & 63;
  if (wid >= T_TOK) return;
  const float* xr = x + (size_t)wid * DM;

  float acc[NE];
#pragma unroll
  for (int e = 0; e < NE; e++) acc[e] = 0.f;

  for (int d = lane; d < DM; d += 64) {
    float xv = xr[d];
    const float* wr = wg + (size_t)d * NE;
#pragma unroll
    for (int e = 0; e < NE; e++) acc[e] += xv * wr[e];
  }
#pragma unroll
  for (int off = 32; off > 0; off >>= 1) {
#pragma unroll
    for (int e = 0; e < NE; e++) acc[e] += __shfl_xor(acc[e], off, 64);
  }
  if (lane == 0) {
    float v[NE];
#pragma unroll
    for (int e = 0; e < NE; e++) v[e] = acc[e] + bg[e];
    int i0 = 0; float v0 = v[0];
#pragma unroll
    for (int e = 1; e < NE; e++) { if (v[e] > v0) { v0 = v[e]; i0 = e; } }
    int i1 = -1; float v1 = -INFINITY;
#pragma unroll
    for (int e = 0; e < NE; e++) { if (e != i0 && v[e] > v1) { v1 = v[e]; i1 = e; } }
    float e1 = expf(v1 - v0);
    float s  = 1.f + e1;
    float w0 = 1.f / s, w1 = e1 / s;
    int p0 = atomicAdd(&cnt[i0], 1);
    perm[i0 * T_TOK + p0] = wid; pw[i0 * T_TOK + p0] = w0;
    int p1 = atomicAdd(&cnt[i1], 1);
    perm[i1 * T_TOK + p1] = wid; pw[i1 * T_TOK + p1] = w1;
  }
}

// ---------------- pad lists to BM multiple + exclusive scan ----------------
__global__ void pad_scan_kernel(const int* __restrict__ cnt, int* __restrict__ cntpad,
                                int* __restrict__ offs, int* __restrict__ perm, float* __restrict__ pw)
{
  if (threadIdx.x == 0) {
    int o = 0;
    for (int e = 0; e < NE; e++) {
      int c  = cnt[e];
      int cp = (c + BM - 1) / BM * BM;
      cntpad[e] = cp;
      offs[e]   = o;
      o += cp;
    }
    offs[NE] = o;
  }
  for (int e = 0; e < NE; e++) {
    int c  = cnt[e];
    int cp = (c + BM - 1) / BM * BM;
    for (int i = c + threadIdx.x; i < cp; i += blockDim.x) {
      perm[e * T_TOK + i] = 0;
      pw[e * T_TOK + i]   = 0.f;
    }
  }
}

// ======== v3 GEMM: global_load_lds staging, triple-buffered LDS, counted vmcnt ========
// Structure (m97-pattern + T4 counted-wait):
//   - linear LDS [128 rows][BK=32] per operand (global_load_lds requires linear dest)
//   - prefetch depth 2: tile kt staged at iter kt-2; 8 loads/wave in flight
//   - ONE raw s_barrier per K-step; vmcnt(4) (never 0) in steady state
//   Race check (3 buffers = 2 barriers of slack):
//     writer of buf b (stage at iter w, post-barrier(w)) vs readers of b (iter w-1,
//     reads complete before barrier(w)); next readers (iter w+2) pass own vmcnt(4)
//     before barrier(w+2), so the whole tile has landed.
template<int PHASE, int KTOT, int NCOLS, int KSPLIT>
__global__ __launch_bounds__(256, 3) void moe_gemm3(
    const unsigned short* __restrict__ Asrc,
    const unsigned short* __restrict__ Bt,     // [E][NCOLS][KTOT] bf16 (transposed)
    const float* __restrict__ bias,
    const int* __restrict__ cntpad, const int* __restrict__ offs,
    const int* __restrict__ perm, const float* __restrict__ pw,
    unsigned short* __restrict__ Hout, float* __restrict__ out)
{
  const int e  = blockIdx.z;
  const int mt = blockIdx.y;
  const int nt = blockIdx.x / KSPLIT;
  const int ks = blockIdx.x % KSPLIT;
  const int cp = cntpad[e];
  if (mt * BM >= cp) return;
  const int tid  = threadIdx.x;
  const int wid  = tid >> 6;
  const int lane = tid & 63;
  const int oe   = offs[e];

  __shared__ unsigned short As[3][BM * BK];
  __shared__ unsigned short Bs[3][BN * BK];

  // staging: wave w owns rows [w*32, w*32+32) of both A and B tiles.
  // one gll16 = 64 lanes x 16B = 16 rows (4 lanes/row): lane -> row l>>2, chunk (l&3)*16B
  const int srow   = wid * 32 + (lane >> 2);
  const int schunk = (lane & 3) * 8;             // elements (8 bf16 = 16B)
  const int kbase0 = ks * (KTOT / KSPLIT);
  const int KITERS = (KTOT / KSPLIT) / BK;       // 32 for both phases

  const unsigned short *srcA0, *srcA1;
  if (PHASE == 1) {
    const int pb = e * T_TOK + mt * BM;
    int t0 = perm[pb + srow];
    int t1 = perm[pb + srow + 16];
    srcA0 = Asrc + (size_t)t0 * KTOT + kbase0 + schunk;
    srcA1 = Asrc + (size_t)t1 * KTOT + kbase0 + schunk;
  } else {
    srcA0 = Asrc + (size_t)(oe + mt * BM + srow) * KTOT + kbase0 + schunk;
    srcA1 = srcA0 + (size_t)16 * KTOT;
  }
  const unsigned short* srcB0 =
      Bt + ((size_t)e * NCOLS + (size_t)nt * BN + srow) * KTOT + kbase0 + schunk;
  const unsigned short* srcB1 = srcB0 + (size_t)16 * KTOT;

  unsigned short* aw = &As[0][0] + (size_t)wid * 32 * BK;  // wave-uniform LDS bases
  unsigned short* bw = &Bs[0][0] + (size_t)wid * 32 * BK;

  auto STAGE = [&](int b, int t) {
    const int ko = t * BK;
    unsigned short* ab = aw + (size_t)b * (BM * BK);
    unsigned short* bb = bw + (size_t)b * (BN * BK);
    gll16(srcA0 + ko, ab);
    gll16(srcA1 + ko, ab + 16 * BK);
    gll16(srcB0 + ko, bb);
    gll16(srcB1 + ko, bb + 16 * BK);
  };

  const int wm   = (wid & 1) * 64;
  const int wn   = (wid >> 1) * 64;
  const int lrow = lane & 15;
  const int lk   = (lane >> 4) * 8;

  f32x4 acc[4][4];
#pragma unroll
  for (int i = 0; i < 4; i++)
#pragma unroll
    for (int j = 0; j < 4; j++) acc[i][j] = (f32x4){0.f, 0.f, 0.f, 0.f};

  // prologue: tiles 0 and 1 in flight (8 loads/wave outstanding)
  STAGE(0, 0);
  STAGE(1, 1);

  int bc = 0;                                    // buffer holding tile kt
  for (int kt = 0; kt < KITERS; ++kt) {
    // wait for tile kt only: keep tile kt+1 (4 loads) in flight across the barrier
    if (kt < KITERS - 1) asm volatile("s_waitcnt vmcnt(4)" ::: "memory");
    else                 asm volatile("s_waitcnt vmcnt(0)" ::: "memory");
    __builtin_amdgcn_s_barrier();
    asm volatile("" ::: "memory");
    if (kt + 2 < KITERS) {                       // stage tile kt+2 (depth-2 prefetch)
      int bs = bc + 2; if (bs >= 3) bs -= 3;
      STAGE(bs, kt + 2);
    }
    const unsigned short* Ac = &As[bc][0];
    const unsigned short* Bc = &Bs[bc][0];
    bf16x8 af[4], bfr[4];
#pragma unroll
    for (int i = 0; i < 4; i++) af[i]  = *(const bf16x8*)&Ac[(wm + i * 16 + lrow) * BK + lk];
#pragma unroll
    for (int j = 0; j < 4; j++) bfr[j] = *(const bf16x8*)&Bc[(wn + j * 16 + lrow) * BK + lk];
#pragma unroll
    for (int i = 0; i < 4; i++)
#pragma unroll
      for (int j = 0; j < 4; j++)
        acc[i][j] = __builtin_amdgcn_mfma_f32_16x16x32_bf16(af[i], bfr[j], acc[i][j], 0, 0, 0);
    if (++bc == 3) bc = 0;
  }

  // epilogue: C/D layout col=lane&15, row=(lane>>4)*4+reg
  const int crow = (lane >> 4) * 4;
  const int ccol = lane & 15;
#pragma unroll
  for (int j = 0; j < 4; j++) {
    const int gn = nt * BN + wn + j * 16 + ccol;
    const float bv = bias[e * NCOLS + gn];
#pragma unroll
    for (int i = 0; i < 4; i++) {
#pragma unroll
      for (int r = 0; r < 4; r++) {
        const int lm = wm + i * 16 + crow + r;
        float v = acc[i][j][r];
        if (PHASE == 1) {
          v += bv;
          v = v > 0.f ? v : 0.f;
          Hout[(size_t)(oe + mt * BM + lm) * NCOLS + gn] = f2bf(v);
        } else {
          if (ks == 0) v += bv;
          const int li    = e * T_TOK + mt * BM + lm;
          const int token = perm[li];
          const float w   = pw[li];
          atomicAdd(&out[(size_t)token * NCOLS + gn], w * v);
        }
      }
    }
  }
}

// ======== v1 GEMM (fallback, f32 weights in-flight) — used only if ws too small ========
template<int PHASE, int KTOT, int NCOLS, int KSPLIT>
__global__ __launch_bounds__(256) void moe_gemm_v1(
    const unsigned short* __restrict__ Asrc,
    const float* __restrict__ Wbase,
    const float* __restrict__ bias,
    const int* __restrict__ cntpad, const int* __restrict__ offs,
    const int* __restrict__ perm, const float* __restrict__ pw,
    unsigned short* __restrict__ Hout, float* __restrict__ out)
{
  const int e  = blockIdx.z;
  const int mt = blockIdx.y;
  const int nt = blockIdx.x / KSPLIT;
  const int ks = blockIdx.x % KSPLIT;
  const int cp = cntpad[e];
  if (mt * BM >= cp) return;
  const int tid = threadIdx.x;
  const int oe  = offs[e];

  __shared__ unsigned short As[BM * LDA];
  __shared__ unsigned short Bs[BN * LDA];

  const int am = tid >> 1;
  const int ak = (tid & 1) * 16;
  size_t arow_off;
  if (PHASE == 1) {
    int token = perm[e * T_TOK + mt * BM + am];
    arow_off = (size_t)token * KTOT;
  } else {
    arow_off = (size_t)(oe + mt * BM + am) * (size_t)KTOT;
  }
  const int bn  = tid & 127;
  const int bk0 = (tid >> 7) * 16;
  const float* Wexp = Wbase + (size_t)e * KTOT * NCOLS + (size_t)nt * BN;
  const int kbase0 = ks * (KTOT / KSPLIT);
  const int KITERS = (KTOT / KSPLIT) / BK;
  const int wid  = tid >> 6;
  const int lane = tid & 63;
  const int wm   = (wid & 1) * 64;
  const int wn   = (wid >> 1) * 64;
  const int lrow = lane & 15;
  const int lk   = (lane >> 4) * 8;

  f32x4 acc[4][4];
#pragma unroll
  for (int i = 0; i < 4; i++)
#pragma unroll
    for (int j = 0; j < 4; j++) acc[i][j] = (f32x4){0.f, 0.f, 0.f, 0.f};

  for (int kt = 0; kt < KITERS; kt++) {
    const int kb = kbase0 + kt * BK;
    {
      const unsigned short* src = Asrc + arow_off + kb + ak;
      uint4 v0 = *(const uint4*)(src);
      uint4 v1 = *(const uint4*)(src + 8);
      *(uint4*)&As[am * LDA + ak]     = v0;
      *(uint4*)&As[am * LDA + ak + 8] = v1;
    }
#pragma unroll
    for (int t2 = 0; t2 < 2; t2++) {
      const int kk = bk0 + t2 * 8;
      const float* wp = Wexp + (size_t)(kb + kk) * NCOLS + bn;
      ushort8 tv;
#pragma unroll
      for (int j = 0; j < 8; j++) tv[j] = f2bf(wp[(size_t)j * NCOLS]);
      *(ushort8*)&Bs[bn * LDA + kk] = tv;
    }
    __syncthreads();
    bf16x8 af[4], bfr[4];
#pragma unroll
    for (int i = 0; i < 4; i++) af[i]  = *(const bf16x8*)&As[(wm + i * 16 + lrow) * LDA + lk];
#pragma unroll
    for (int j = 0; j < 4; j++) bfr[j] = *(const bf16x8*)&Bs[(wn + j * 16 + lrow) * LDA + lk];
#pragma unroll
    for (int i = 0; i < 4; i++)
#pragma unroll
      for (int j = 0; j < 4; j++)
        acc[i][j] = __builtin_amdgcn_mfma_f32_16x16x32_bf16(af[i], bfr[j], acc[i][j], 0, 0, 0);
    __syncthreads();
  }

  const int crow = (lane >> 4) * 4;
  const int ccol = lane & 15;
#pragma unroll
  for (int j = 0; j < 4; j++) {
    const int gn = nt * BN + wn + j * 16 + ccol;
    const float bv = bias[e * NCOLS + gn];
#pragma unroll
    for (int i = 0; i < 4; i++) {
#pragma unroll
      for (int r = 0; r < 4; r++) {
        const int lm = wm + i * 16 + crow + r;
        float v = acc[i][j][r];
        if (PHASE == 1) {
          v += bv;
          v = v > 0.f ? v : 0.f;
          Hout[(size_t)(oe + mt * BM + lm) * NCOLS + gn] = f2bf(v);
        } else {
          if (ks == 0) v += bv;
          const int li    = e * T_TOK + mt * BM + lm;
          const int token = perm[li];
          const float w   = pw[li];
          atomicAdd(&out[(size_t)token * NCOLS + gn], w * v);
        }
      }
    }
  }
}

extern "C" void kernel_launch(void* const* d_in, const int* in_sizes, int n_in,
                              void* d_out, int out_size, void* d_ws, size_t ws_size,
                              hipStream_t stream) {
  const float* x  = (const float*)d_in[0];
  const float* wg = (const float*)d_in[1];
  const float* bg = (const float*)d_in[2];
  const float* w1 = (const float*)d_in[3];
  const float* b1 = (const float*)d_in[4];
  const float* w2 = (const float*)d_in[5];
  const float* b2 = (const float*)d_in[6];
  float* out = (float*)d_out;

  // ---- workspace layout ----
  const size_t XB_BYTES   = (size_t)T_TOK * DM * 2;          // 4 MB
  const size_t PERM_BYTES = (size_t)NE * T_TOK * 4;          // 64 KB
  const size_t PW_BYTES   = (size_t)NE * T_TOK * 4;          // 64 KB
  const size_t H_BYTES    = (size_t)(2 * T_TOK + NE * BM) * DF * 2;  // 40 MB
  const size_t W1T_BYTES  = (size_t)NE * DF * DM * 2;        // 64 MB
  const size_t W2T_BYTES  = (size_t)NE * DM * DF * 2;        // 64 MB

  char* wsp = (char*)d_ws;
  size_t off = 0;
  unsigned short* xb = (unsigned short*)(wsp + off); off += XB_BYTES;
  int*   cnt    = (int*)(wsp + off); off += 256;             // cnt/cntpad/offs packed
  int*   cntpad = cnt + 8;
  int*   offs   = cnt + 16;
  int*   perm   = (int*)(wsp + off);   off += PERM_BYTES;
  float* pwt    = (float*)(wsp + off); off += PW_BYTES;
  unsigned short* H   = (unsigned short*)(wsp + off); off += H_BYTES;
  unsigned short* w1t = (unsigned short*)(wsp + off); off += W1T_BYTES;
  unsigned short* w2t = (unsigned short*)(wsp + off); off += W2T_BYTES;
  const size_t REQUIRED = off;

  hipMemsetAsync(cnt, 0, 256, stream);
  hipMemsetAsync(d_out, 0, (size_t)T_TOK * DM * 4, stream);

  convert_x_kernel<<<(T_TOK * DM / 8) / 256, 256, 0, stream>>>(x, xb);
  gating_kernel<<<T_TOK / 4, 256, 0, stream>>>(x, wg, bg, cnt, perm, pwt);
  pad_scan_kernel<<<1, 256, 0, stream>>>(cnt, cntpad, offs, perm, pwt);

  if (ws_size >= REQUIRED) {
    // convert + transpose weights to bf16 [E][N][K]
    transpose_convert<DM, DF><<<dim3(DF / 128, DM / 32, NE), 256, 0, stream>>>(w1, w1t);
    transpose_convert<DF, DM><<<dim3(DM / 128, DF / 32, NE), 256, 0, stream>>>(w2, w2t);

    moe_gemm3<1, DM, DF, 1><<<dim3(DF / BN, T_TOK / BM, NE), 256, 0, stream>>>(
        xb, w1t, b1, cntpad, offs, perm, pwt, H, nullptr);
    moe_gemm3<2, DF, DM, 4><<<dim3((DM / BN) * 4, T_TOK / BM, NE), 256, 0, stream>>>(
        H, w2t, b2, cntpad, offs, perm, pwt, nullptr, out);
  } else {
    // fallback: round-1 path (needs only ~46 MB of ws)
    moe_gemm_v1<1, DM, DF, 1><<<dim3(DF / BN, T_TOK / BM, NE), 256, 0, stream>>>(
        xb, w1, b1, cntpad, offs, perm, pwt, H, nullptr);
    moe_gemm_v1<2, DF, DM, 4><<<dim3((DM / BN) * 4, T_TOK / BM, NE), 256, 0, stream>>>(
        H, w2, b2, cntpad, offs, perm, pwt, nullptr, out);
  }
}

// Round 2
// 629.359 us; speedup vs baseline: 1.1648x; 1.1648x over previous
//
#include <hip/hip_runtime.h>
#include <hip/hip_bf16.h>
#include <math.h>

#define T_TOK 2048
#define DM    1024
#define DF    4096
#define NE    8
#define BM    128
#define BN    128
#define BK    64
#define LDA2  72   // LDS row stride (144B): rows 8 apart alias 2-way (free), b128-aligned
#define LDAV1 40   // v1 fallback LDS stride

typedef __attribute__((ext_vector_type(8))) short          bf16x8;
typedef __attribute__((ext_vector_type(8))) unsigned short ushort8;
typedef __attribute__((ext_vector_type(4))) float          f32x4;

__device__ __forceinline__ unsigned short f2bf(float f) {
  unsigned u = __builtin_bit_cast(unsigned, f);
  unsigned r = u + 0x7fffu + ((u >> 16) & 1u);   // RNE
  return (unsigned short)(r >> 16);
}

// ---------------- x f32 -> bf16 ----------------
__global__ void convert_x_kernel(const float* __restrict__ x, unsigned short* __restrict__ xb) {
  int i = blockIdx.x * blockDim.x + threadIdx.x;   // one thread per 8 elements
  const float* src = x + (size_t)i * 8;
  float4 a = *(const float4*)(src);
  float4 b = *(const float4*)(src + 4);
  ushort8 v;
  v[0] = f2bf(a.x); v[1] = f2bf(a.y); v[2] = f2bf(a.z); v[3] = f2bf(a.w);
  v[4] = f2bf(b.x); v[5] = f2bf(b.y); v[6] = f2bf(b.z); v[7] = f2bf(b.w);
  *(ushort8*)(xb + (size_t)i * 8) = v;
}

// ---------------- weight convert + TILE-PACK: W[E][K][N] f32 -> Wt[e][n/128][k/64][128][64] bf16 ----
// Each (nt,kt) output tile is a CONTIGUOUS 16KB block so the GEMM streams B sequentially.
template<int K, int N>
__global__ __launch_bounds__(256) void transpose_convert_packed(
    const float* __restrict__ W, unsigned short* __restrict__ Wt)
{
  const int e  = blockIdx.z;
  const int kt = blockIdx.y;            // K/64 tiles
  const int nt = blockIdx.x;            // N/128 tiles
  const int k0 = kt * 64;
  const int n0 = nt * 128;
  const float* Wp = W + (size_t)e * K * N;
  __shared__ float Ls[64][129];
  const int tid = threadIdx.x;
  {  // load 64k x 128n tile, float4-coalesced
    const int kl = tid >> 5;            // 0..7
    const int nl = (tid & 31) * 4;
#pragma unroll
    for (int p = 0; p < 8; p++) {
      const int k = kl + p * 8;
      float4 v = *(const float4*)(Wp + (size_t)(k0 + k) * N + n0 + nl);
      Ls[k][nl + 0] = v.x; Ls[k][nl + 1] = v.y; Ls[k][nl + 2] = v.z; Ls[k][nl + 3] = v.w;
    }
  }
  __syncthreads();
  unsigned short* Wo = Wt + ((((size_t)e * (N / 128) + nt) * (K / 64) + kt) * 128) * 64;
  {  // store packed [n][64k]: column reads stride-129, conflict-free
    const int n  = tid & 127;
    const int c0 = tid >> 7;            // 0..1
#pragma unroll
    for (int p = 0; p < 4; p++) {
      const int c = c0 + p * 2;         // 0..7 (8 k-elems each)
      ushort8 o;
#pragma unroll
      for (int j = 0; j < 8; j++) o[j] = f2bf(Ls[c * 8 + j][n]);
      *(ushort8*)(Wo + (size_t)n * 64 + c * 8) = o;
    }
  }
}

// ---------------- gating: one wave per token ----------------
__global__ __launch_bounds__(256) void gating_kernel(
    const float* __restrict__ x, const float* __restrict__ wg, const float* __restrict__ bg,
    int* __restrict__ cnt, int* __restrict__ perm, float* __restrict__ pw)
{
  int wid  = (blockIdx.x * blockDim.x + threadIdx.x) >> 6;   // token
  int lane = threadIdx.x & 63;
  if (wid >= T_TOK) return;
  const float* xr = x + (size_t)wid * DM;

  float acc[NE];
#pragma unroll
  for (int e = 0; e < NE; e++) acc[e] = 0.f;

  for (int d = lane; d < DM; d += 64) {
    float xv = xr[d];
    const float* wr = wg + (size_t)d * NE;
#pragma unroll
    for (int e = 0; e < NE; e++) acc[e] += xv * wr[e];
  }
#pragma unroll
  for (int off = 32; off > 0; off >>= 1) {
#pragma unroll
    for (int e = 0; e < NE; e++) acc[e] += __shfl_xor(acc[e], off, 64);
  }
  if (lane == 0) {
    float v[NE];
#pragma unroll
    for (int e = 0; e < NE; e++) v[e] = acc[e] + bg[e];
    int i0 = 0; float v0 = v[0];
#pragma unroll
    for (int e = 1; e < NE; e++) { if (v[e] > v0) { v0 = v[e]; i0 = e; } }
    int i1 = -1; float v1 = -INFINITY;
#pragma unroll
    for (int e = 0; e < NE; e++) { if (e != i0 && v[e] > v1) { v1 = v[e]; i1 = e; } }
    float e1 = expf(v1 - v0);
    float s  = 1.f + e1;
    float w0 = 1.f / s, w1 = e1 / s;
    int p0 = atomicAdd(&cnt[i0], 1);
    perm[i0 * T_TOK + p0] = wid; pw[i0 * T_TOK + p0] = w0;
    int p1 = atomicAdd(&cnt[i1], 1);
    perm[i1 * T_TOK + p1] = wid; pw[i1 * T_TOK + p1] = w1;
  }
}

// ---------------- pad lists to BM multiple + exclusive scan ----------------
__global__ void pad_scan_kernel(const int* __restrict__ cnt, int* __restrict__ cntpad,
                                int* __restrict__ offs, int* __restrict__ perm, float* __restrict__ pw)
{
  if (threadIdx.x == 0) {
    int o = 0;
    for (int e = 0; e < NE; e++) {
      int c  = cnt[e];
      int cp = (c + BM - 1) / BM * BM;
      cntpad[e] = cp;
      offs[e]   = o;
      o += cp;
    }
    offs[NE] = o;
  }
  for (int e = 0; e < NE; e++) {
    int c  = cnt[e];
    int cp = (c + BM - 1) / BM * BM;
    for (int i = c + threadIdx.x; i < cp; i += blockDim.x) {
      perm[e * T_TOK + i] = 0;
      pw[e * T_TOK + i]   = 0.f;
    }
  }
}

// ======== v4 GEMM: BK=64, tile-packed operands, depth-1 register prefetch (proven structure) ========
// PHASE 1: H = relu(X_e * W1 + b1), H stored TILE-PACKED [rb][kt][128][64]
// PHASE 2: out[token] += w * (H_e * W2 + b2), A read from packed H
// B always tile-packed [e][nt][kt][128][64] -> staging is fully sequential (thread tid reads base+tid*64B)
template<int PHASE, int KTOT, int NCOLS, int KSPLIT>
__global__ __launch_bounds__(256, 3) void moe_gemm4(
    const unsigned short* __restrict__ Asrc,
    const unsigned short* __restrict__ Bt,
    const float* __restrict__ bias,
    const int* __restrict__ cntpad, const int* __restrict__ offs,
    const int* __restrict__ perm, const float* __restrict__ pw,
    unsigned short* __restrict__ Hout, float* __restrict__ out)
{
  const int e  = blockIdx.z;
  const int mt = blockIdx.y;
  const int nt = blockIdx.x / KSPLIT;
  const int ks = blockIdx.x % KSPLIT;
  const int cp = cntpad[e];
  if (mt * BM >= cp) return;
  const int tid = threadIdx.x;
  const int oe  = offs[e];

  __shared__ unsigned short As[BM * LDA2];
  __shared__ unsigned short Bs[BN * LDA2];

  // staging map: thread -> row am, 64B half ak (32 elems). Packed tiles: contiguous across tid.
  const int am = tid >> 1;
  const int ak = (tid & 1) * 32;
  const int kb0 = ks * (KTOT / KSPLIT);
  const int KITERS = (KTOT / KSPLIT) / BK;

  const unsigned short* Ap;
  size_t APITCH;
  if (PHASE == 1) {
    int token = perm[e * T_TOK + mt * BM + am];
    Ap = Asrc + (size_t)token * KTOT + kb0 + ak;     // row-major xb, 128B/row/iter
    APITCH = BK;
  } else {
    const size_t rb = (size_t)(oe >> 7) + mt;        // H row-block (oe is 128-multiple)
    Ap = Asrc + (((rb * (KTOT / 64) + (kb0 >> 6)) * 128 + am) * 64) + ak;
    APITCH = (size_t)128 * 64;                       // next k-tile
  }
  const unsigned short* Bp =
      Bt + ((((size_t)e * (NCOLS / 128) + nt) * (KTOT / 64) + (kb0 >> 6)) * 128 + am) * 64 + ak;

  const int wid  = tid >> 6;
  const int lane = tid & 63;
  const int wm   = (wid & 1) * 64;
  const int wn   = (wid >> 1) * 64;
  const int lrow = lane & 15;
  const int lk   = (lane >> 4) * 8;

  f32x4 acc[4][4];
#pragma unroll
  for (int i = 0; i < 4; i++)
#pragma unroll
    for (int j = 0; j < 4; j++) acc[i][j] = (f32x4){0.f, 0.f, 0.f, 0.f};

  uint4 pa0, pa1, pa2, pa3, pb0, pb1, pb2, pb3;
  auto LOADT = [&](int kt) {
    const unsigned short* a = Ap + (size_t)kt * APITCH;
    const unsigned short* b = Bp + (size_t)kt * (128 * 64);
    pa0 = *(const uint4*)(a);      pa1 = *(const uint4*)(a + 8);
    pa2 = *(const uint4*)(a + 16); pa3 = *(const uint4*)(a + 24);
    pb0 = *(const uint4*)(b);      pb1 = *(const uint4*)(b + 8);
    pb2 = *(const uint4*)(b + 16); pb3 = *(const uint4*)(b + 24);
  };
  auto STORET = [&]() {
    unsigned short* as = &As[am * LDA2 + ak];
    unsigned short* bs = &Bs[am * LDA2 + ak];
    *(uint4*)(as)      = pa0; *(uint4*)(as + 8)  = pa1;
    *(uint4*)(as + 16) = pa2; *(uint4*)(as + 24) = pa3;
    *(uint4*)(bs)      = pb0; *(uint4*)(bs + 8)  = pb1;
    *(uint4*)(bs + 16) = pb2; *(uint4*)(bs + 24) = pb3;
  };

  LOADT(0);
  STORET();
  for (int kt = 0; kt < KITERS; kt++) {
    __syncthreads();                          // tile kt visible
    if (kt + 1 < KITERS) LOADT(kt + 1);       // prefetch next tile into regs
#pragma unroll
    for (int ksb = 0; ksb < 2; ksb++) {       // BK=64 = two K=32 MFMA sub-steps
      bf16x8 af[4], bfr[4];
#pragma unroll
      for (int i = 0; i < 4; i++)
        af[i]  = *(const bf16x8*)&As[(wm + i * 16 + lrow) * LDA2 + ksb * 32 + lk];
#pragma unroll
      for (int j = 0; j < 4; j++)
        bfr[j] = *(const bf16x8*)&Bs[(wn + j * 16 + lrow) * LDA2 + ksb * 32 + lk];
#pragma unroll
      for (int i = 0; i < 4; i++)
#pragma unroll
        for (int j = 0; j < 4; j++)
          acc[i][j] = __builtin_amdgcn_mfma_f32_16x16x32_bf16(af[i], bfr[j], acc[i][j], 0, 0, 0);
    }
    __syncthreads();                          // frags consumed; safe to overwrite LDS
    if (kt + 1 < KITERS) STORET();
  }

  // epilogue: C/D layout col=lane&15, row=(lane>>4)*4+reg
  const int crow = (lane >> 4) * 4;
  const int ccol = lane & 15;
  const size_t rbh = (size_t)(oe >> 7) + mt;   // H row-block for packed store
#pragma unroll
  for (int j = 0; j < 4; j++) {
    const int gn = nt * BN + wn + j * 16 + ccol;
    const float bv = bias[e * NCOLS + gn];
#pragma unroll
    for (int i = 0; i < 4; i++) {
#pragma unroll
      for (int r = 0; r < 4; r++) {
        const int lm = wm + i * 16 + crow + r;
        float v = acc[i][j][r];
        if (PHASE == 1) {
          v += bv;
          v = v > 0.f ? v : 0.f;
          // packed H: [rbh][gn>>6][lm][gn&63]
          Hout[(((rbh * (NCOLS / 64) + (gn >> 6)) * 128 + lm) * 64) + (gn & 63)] = f2bf(v);
        } else {
          if (ks == 0) v += bv;
          const int li    = e * T_TOK + mt * BM + lm;
          const int token = perm[li];
          const float w   = pw[li];
          atomicAdd(&out[(size_t)token * NCOLS + gn], w * v);
        }
      }
    }
  }
}

// ======== v1 GEMM (fallback, f32 weights in-flight, row-major H) — used only if ws too small ========
template<int PHASE, int KTOT, int NCOLS, int KSPLIT>
__global__ __launch_bounds__(256) void moe_gemm_v1(
    const unsigned short* __restrict__ Asrc,
    const float* __restrict__ Wbase,
    const float* __restrict__ bias,
    const int* __restrict__ cntpad, const int* __restrict__ offs,
    const int* __restrict__ perm, const float* __restrict__ pw,
    unsigned short* __restrict__ Hout, float* __restrict__ out)
{
  const int e  = blockIdx.z;
  const int mt = blockIdx.y;
  const int nt = blockIdx.x / KSPLIT;
  const int ks = blockIdx.x % KSPLIT;
  const int cp = cntpad[e];
  if (mt * BM >= cp) return;
  const int tid = threadIdx.x;
  const int oe  = offs[e];

  __shared__ unsigned short As[BM * LDAV1];
  __shared__ unsigned short Bs[BN * LDAV1];

  const int am = tid >> 1;
  const int ak = (tid & 1) * 16;
  size_t arow_off;
  if (PHASE == 1) {
    int token = perm[e * T_TOK + mt * BM + am];
    arow_off = (size_t)token * KTOT;
  } else {
    arow_off = (size_t)(oe + mt * BM + am) * (size_t)KTOT;
  }
  const int bn  = tid & 127;
  const int bk0 = (tid >> 7) * 16;
  const float* Wexp = Wbase + (size_t)e * KTOT * NCOLS + (size_t)nt * BN;
  const int kbase0 = ks * (KTOT / KSPLIT);
  const int KITERS = (KTOT / KSPLIT) / 32;
  const int wid  = tid >> 6;
  const int lane = tid & 63;
  const int wm   = (wid & 1) * 64;
  const int wn   = (wid >> 1) * 64;
  const int lrow = lane & 15;
  const int lk   = (lane >> 4) * 8;

  f32x4 acc[4][4];
#pragma unroll
  for (int i = 0; i < 4; i++)
#pragma unroll
    for (int j = 0; j < 4; j++) acc[i][j] = (f32x4){0.f, 0.f, 0.f, 0.f};

  for (int kt = 0; kt < KITERS; kt++) {
    const int kb = kbase0 + kt * 32;
    {
      const unsigned short* src = Asrc + arow_off + kb + ak;
      uint4 v0 = *(const uint4*)(src);
      uint4 v1 = *(const uint4*)(src + 8);
      *(uint4*)&As[am * LDAV1 + ak]     = v0;
      *(uint4*)&As[am * LDAV1 + ak + 8] = v1;
    }
#pragma unroll
    for (int t2 = 0; t2 < 2; t2++) {
      const int kk = bk0 + t2 * 8;
      const float* wp = Wexp + (size_t)(kb + kk) * NCOLS + bn;
      ushort8 tv;
#pragma unroll
      for (int j = 0; j < 8; j++) tv[j] = f2bf(wp[(size_t)j * NCOLS]);
      *(ushort8*)&Bs[bn * LDAV1 + kk] = tv;
    }
    __syncthreads();
    bf16x8 af[4], bfr[4];
#pragma unroll
    for (int i = 0; i < 4; i++) af[i]  = *(const bf16x8*)&As[(wm + i * 16 + lrow) * LDAV1 + lk];
#pragma unroll
    for (int j = 0; j < 4; j++) bfr[j] = *(const bf16x8*)&Bs[(wn + j * 16 + lrow) * LDAV1 + lk];
#pragma unroll
    for (int i = 0; i < 4; i++)
#pragma unroll
      for (int j = 0; j < 4; j++)
        acc[i][j] = __builtin_amdgcn_mfma_f32_16x16x32_bf16(af[i], bfr[j], acc[i][j], 0, 0, 0);
    __syncthreads();
  }

  const int crow = (lane >> 4) * 4;
  const int ccol = lane & 15;
#pragma unroll
  for (int j = 0; j < 4; j++) {
    const int gn = nt * BN + wn + j * 16 + ccol;
    const float bv = bias[e * NCOLS + gn];
#pragma unroll
    for (int i = 0; i < 4; i++) {
#pragma unroll
      for (int r = 0; r < 4; r++) {
        const int lm = wm + i * 16 + crow + r;
        float v = acc[i][j][r];
        if (PHASE == 1) {
          v += bv;
          v = v > 0.f ? v : 0.f;
          Hout[(size_t)(oe + mt * BM + lm) * NCOLS + gn] = f2bf(v);
        } else {
          if (ks == 0) v += bv;
          const int li    = e * T_TOK + mt * BM + lm;
          const int token = perm[li];
          const float w   = pw[li];
          atomicAdd(&out[(size_t)token * NCOLS + gn], w * v);
        }
      }
    }
  }
}

extern "C" void kernel_launch(void* const* d_in, const int* in_sizes, int n_in,
                              void* d_out, int out_size, void* d_ws, size_t ws_size,
                              hipStream_t stream) {
  const float* x  = (const float*)d_in[0];
  const float* wg = (const float*)d_in[1];
  const float* bg = (const float*)d_in[2];
  const float* w1 = (const float*)d_in[3];
  const float* b1 = (const float*)d_in[4];
  const float* w2 = (const float*)d_in[5];
  const float* b2 = (const float*)d_in[6];
  float* out = (float*)d_out;

  // ---- workspace layout ----
  const size_t XB_BYTES   = (size_t)T_TOK * DM * 2;          // 4 MB
  const size_t PERM_BYTES = (size_t)NE * T_TOK * 4;          // 64 KB
  const size_t PW_BYTES   = (size_t)NE * T_TOK * 4;          // 64 KB
  const size_t H_BYTES    = (size_t)(2 * T_TOK + NE * BM) * DF * 2;  // 40 MB (packed layout, same bytes)
  const size_t W1T_BYTES  = (size_t)NE * DF * DM * 2;        // 64 MB
  const size_t W2T_BYTES  = (size_t)NE * DM * DF * 2;        // 64 MB

  char* wsp = (char*)d_ws;
  size_t off = 0;
  unsigned short* xb = (unsigned short*)(wsp + off); off += XB_BYTES;
  int*   cnt    = (int*)(wsp + off); off += 256;             // cnt/cntpad/offs packed
  int*   cntpad = cnt + 8;
  int*   offs   = cnt + 16;
  int*   perm   = (int*)(wsp + off);   off += PERM_BYTES;
  float* pwt    = (float*)(wsp + off); off += PW_BYTES;
  unsigned short* H   = (unsigned short*)(wsp + off); off += H_BYTES;
  unsigned short* w1t = (unsigned short*)(wsp + off); off += W1T_BYTES;
  unsigned short* w2t = (unsigned short*)(wsp + off); off += W2T_BYTES;
  const size_t REQUIRED = off;

  hipMemsetAsync(cnt, 0, 256, stream);
  hipMemsetAsync(d_out, 0, (size_t)T_TOK * DM * 4, stream);

  convert_x_kernel<<<(T_TOK * DM / 8) / 256, 256, 0, stream>>>(x, xb);
  gating_kernel<<<T_TOK / 4, 256, 0, stream>>>(x, wg, bg, cnt, perm, pwt);
  pad_scan_kernel<<<1, 256, 0, stream>>>(cnt, cntpad, offs, perm, pwt);

  if (ws_size >= REQUIRED) {
    // convert + tile-pack weights to bf16 [e][nt][kt][128][64]
    transpose_convert_packed<DM, DF><<<dim3(DF / 128, DM / 64, NE), 256, 0, stream>>>(w1, w1t);
    transpose_convert_packed<DF, DM><<<dim3(DM / 128, DF / 64, NE), 256, 0, stream>>>(w2, w2t);

    moe_gemm4<1, DM, DF, 1><<<dim3(DF / BN, T_TOK / BM, NE), 256, 0, stream>>>(
        xb, w1t, b1, cntpad, offs, perm, pwt, H, nullptr);
    moe_gemm4<2, DF, DM, 2><<<dim3((DM / BN) * 2, T_TOK / BM, NE), 256, 0, stream>>>(
        H, w2t, b2, cntpad, offs, perm, pwt, nullptr, out);
  } else {
    // fallback: v1 path (needs only ~46 MB of ws), row-major H throughout
    moe_gemm_v1<1, DM, DF, 1><<<dim3(DF / BN, T_TOK / BM, NE), 256, 0, stream>>>(
        xb, w1, b1, cntpad, offs, perm, pwt, H, nullptr);
    moe_gemm_v1<2, DF, DM, 4><<<dim3((DM / BN) * 4, T_TOK / BM, NE), 256, 0, stream>>>(
        H, w2, b2, cntpad, offs, perm, pwt, nullptr, out);
  }
}

// Round 3
// 515.772 us; speedup vs baseline: 1.4213x; 1.2202x over previous
//
#include <hip/hip_runtime.h>
#include <hip/hip_bf16.h>
#include <math.h>

#define T_TOK 2048
#define DM    1024
#define DF    4096
#define NE    8
#define BM    128
#define BN    128
#define BK    64
#define LDA2  72   // LDS row stride (144B): rows 8 apart alias 2-way (free), b128-aligned
#define LDAV1 40   // v1 fallback LDS stride
#define YROWS 5120 // max padded rows (4096 + 8*127 rounded up)

typedef __attribute__((ext_vector_type(8))) short          bf16x8;
typedef __attribute__((ext_vector_type(8))) unsigned short ushort8;
typedef __attribute__((ext_vector_type(4))) float          f32x4;

__device__ __forceinline__ unsigned short f2bf(float f) {
  unsigned u = __builtin_bit_cast(unsigned, f);
  unsigned r = u + 0x7fffu + ((u >> 16) & 1u);   // RNE
  return (unsigned short)(r >> 16);
}

// ---------------- x f32 -> bf16 ----------------
__global__ void convert_x_kernel(const float* __restrict__ x, unsigned short* __restrict__ xb) {
  int i = blockIdx.x * blockDim.x + threadIdx.x;   // one thread per 8 elements
  const float* src = x + (size_t)i * 8;
  float4 a = *(const float4*)(src);
  float4 b = *(const float4*)(src + 4);
  ushort8 v;
  v[0] = f2bf(a.x); v[1] = f2bf(a.y); v[2] = f2bf(a.z); v[3] = f2bf(a.w);
  v[4] = f2bf(b.x); v[5] = f2bf(b.y); v[6] = f2bf(b.z); v[7] = f2bf(b.w);
  *(ushort8*)(xb + (size_t)i * 8) = v;
}

// ---------------- weight convert + TILE-PACK: W[E][K][N] f32 -> Wt[e][n/128][k/64][128][64] bf16 ----
template<int K, int N>
__global__ __launch_bounds__(256) void transpose_convert_packed(
    const float* __restrict__ W, unsigned short* __restrict__ Wt)
{
  const int e  = blockIdx.z;
  const int kt = blockIdx.y;            // K/64 tiles
  const int nt = blockIdx.x;            // N/128 tiles
  const int k0 = kt * 64;
  const int n0 = nt * 128;
  const float* Wp = W + (size_t)e * K * N;
  __shared__ float Ls[64][129];
  const int tid = threadIdx.x;
  {
    const int kl = tid >> 5;
    const int nl = (tid & 31) * 4;
#pragma unroll
    for (int p = 0; p < 8; p++) {
      const int k = kl + p * 8;
      float4 v = *(const float4*)(Wp + (size_t)(k0 + k) * N + n0 + nl);
      Ls[k][nl + 0] = v.x; Ls[k][nl + 1] = v.y; Ls[k][nl + 2] = v.z; Ls[k][nl + 3] = v.w;
    }
  }
  __syncthreads();
  unsigned short* Wo = Wt + ((((size_t)e * (N / 128) + nt) * (K / 64) + kt) * 128) * 64;
  {
    const int n  = tid & 127;
    const int c0 = tid >> 7;
#pragma unroll
    for (int p = 0; p < 4; p++) {
      const int c = c0 + p * 2;
      ushort8 o;
#pragma unroll
      for (int j = 0; j < 8; j++) o[j] = f2bf(Ls[c * 8 + j][n]);
      *(ushort8*)(Wo + (size_t)n * 64 + c * 8) = o;
    }
  }
}

// ---------------- gating: one wave per token ----------------
// Also records per-token slot bookkeeping for the atomic-free combine:
//   tok2slot[2t+s] = (expert<<16) | position-in-expert-list, tokw[2t+s] = weight
__global__ __launch_bounds__(256) void gating_kernel(
    const float* __restrict__ x, const float* __restrict__ wg, const float* __restrict__ bg,
    int* __restrict__ cnt, int* __restrict__ perm, float* __restrict__ pw,
    int* __restrict__ tok2slot, float* __restrict__ tokw)
{
  int wid  = (blockIdx.x * blockDim.x + threadIdx.x) >> 6;   // token
  int lane = threadIdx.x & 63;
  if (wid >= T_TOK) return;
  const float* xr = x + (size_t)wid * DM;

  float acc[NE];
#pragma unroll
  for (int e = 0; e < NE; e++) acc[e] = 0.f;

  for (int d = lane; d < DM; d += 64) {
    float xv = xr[d];
    const float* wr = wg + (size_t)d * NE;
#pragma unroll
    for (int e = 0; e < NE; e++) acc[e] += xv * wr[e];
  }
#pragma unroll
  for (int off = 32; off > 0; off >>= 1) {
#pragma unroll
    for (int e = 0; e < NE; e++) acc[e] += __shfl_xor(acc[e], off, 64);
  }
  if (lane == 0) {
    float v[NE];
#pragma unroll
    for (int e = 0; e < NE; e++) v[e] = acc[e] + bg[e];
    int i0 = 0; float v0 = v[0];
#pragma unroll
    for (int e = 1; e < NE; e++) { if (v[e] > v0) { v0 = v[e]; i0 = e; } }
    int i1 = -1; float v1 = -INFINITY;
#pragma unroll
    for (int e = 0; e < NE; e++) { if (e != i0 && v[e] > v1) { v1 = v[e]; i1 = e; } }
    float e1 = expf(v1 - v0);
    float s  = 1.f + e1;
    float w0 = 1.f / s, w1 = e1 / s;
    int p0 = atomicAdd(&cnt[i0], 1);
    perm[i0 * T_TOK + p0] = wid; pw[i0 * T_TOK + p0] = w0;
    int p1 = atomicAdd(&cnt[i1], 1);
    perm[i1 * T_TOK + p1] = wid; pw[i1 * T_TOK + p1] = w1;
    tok2slot[2 * wid + 0] = (i0 << 16) | p0;  tokw[2 * wid + 0] = w0;
    tok2slot[2 * wid + 1] = (i1 << 16) | p1;  tokw[2 * wid + 1] = w1;
  }
}

// ---------------- pad lists to BM multiple + exclusive scan ----------------
__global__ void pad_scan_kernel(const int* __restrict__ cnt, int* __restrict__ cntpad,
                                int* __restrict__ offs, int* __restrict__ perm, float* __restrict__ pw)
{
  if (threadIdx.x == 0) {
    int o = 0;
    for (int e = 0; e < NE; e++) {
      int c  = cnt[e];
      int cp = (c + BM - 1) / BM * BM;
      cntpad[e] = cp;
      offs[e]   = o;
      o += cp;
    }
    offs[NE] = o;
  }
  for (int e = 0; e < NE; e++) {
    int c  = cnt[e];
    int cp = (c + BM - 1) / BM * BM;
    for (int i = c + threadIdx.x; i < cp; i += blockDim.x) {
      perm[e * T_TOK + i] = 0;
      pw[e * T_TOK + i]   = 0.f;
    }
  }
}

// ---------------- atomic-free combine: out[t] = sum_s w_s * (y0[row_s] + y1[row_s]) ----------------
// one block per token, 256 threads x float4 = 1024 cols
__global__ __launch_bounds__(256) void combine_kernel(
    const float* __restrict__ y0, const float* __restrict__ y1,
    const int* __restrict__ offs, const int* __restrict__ tok2slot,
    const float* __restrict__ tokw, float* __restrict__ out)
{
  const int t = blockIdx.x;
  const int d = threadIdx.x * 4;
  const int s0 = tok2slot[2 * t + 0];
  const int s1 = tok2slot[2 * t + 1];
  const float w0 = tokw[2 * t + 0];
  const float w1 = tokw[2 * t + 1];
  const size_t r0 = (size_t)(offs[s0 >> 16] + (s0 & 0xffff)) * DM + d;
  const size_t r1 = (size_t)(offs[s1 >> 16] + (s1 & 0xffff)) * DM + d;
  float4 a0 = *(const float4*)(y0 + r0);
  float4 b0 = *(const float4*)(y1 + r0);
  float4 a1 = *(const float4*)(y0 + r1);
  float4 b1 = *(const float4*)(y1 + r1);
  float4 o;
  o.x = w0 * (a0.x + b0.x) + w1 * (a1.x + b1.x);
  o.y = w0 * (a0.y + b0.y) + w1 * (a1.y + b1.y);
  o.z = w0 * (a0.z + b0.z) + w1 * (a1.z + b1.z);
  o.w = w0 * (a0.w + b0.w) + w1 * (a1.w + b1.w);
  *(float4*)(out + (size_t)t * DM + d) = o;
}

// ======== v5 GEMM: BK=64, tile-packed operands, depth-1 register prefetch ========
// PHASE 1: H = relu(X_e * W1 + b1), H stored TILE-PACKED [rb][kt][128][64]
// PHASE 2: y[ks][row] = H_e * W2 (+ b2 if ks==0) -- PLAIN f32 stores, no atomics
template<int PHASE, int KTOT, int NCOLS, int KSPLIT>
__global__ __launch_bounds__(256, 3) void moe_gemm5(
    const unsigned short* __restrict__ Asrc,
    const unsigned short* __restrict__ Bt,
    const float* __restrict__ bias,
    const int* __restrict__ cntpad, const int* __restrict__ offs,
    const int* __restrict__ perm,
    unsigned short* __restrict__ Hout, float* __restrict__ yout)
{
  const int e  = blockIdx.z;
  const int mt = blockIdx.y;
  const int nt = blockIdx.x / KSPLIT;
  const int ks = blockIdx.x % KSPLIT;
  const int cp = cntpad[e];
  if (mt * BM >= cp) return;
  const int tid = threadIdx.x;
  const int oe  = offs[e];

  __shared__ unsigned short As[BM * LDA2];
  __shared__ unsigned short Bs[BN * LDA2];

  const int am = tid >> 1;
  const int ak = (tid & 1) * 32;
  const int kb0 = ks * (KTOT / KSPLIT);
  const int KITERS = (KTOT / KSPLIT) / BK;

  const unsigned short* Ap;
  size_t APITCH;
  if (PHASE == 1) {
    int token = perm[e * T_TOK + mt * BM + am];
    Ap = Asrc + (size_t)token * KTOT + kb0 + ak;
    APITCH = BK;
  } else {
    const size_t rb = (size_t)(oe >> 7) + mt;        // H row-block (oe is 128-multiple)
    Ap = Asrc + (((rb * (KTOT / 64) + (kb0 >> 6)) * 128 + am) * 64) + ak;
    APITCH = (size_t)128 * 64;
  }
  const unsigned short* Bp =
      Bt + ((((size_t)e * (NCOLS / 128) + nt) * (KTOT / 64) + (kb0 >> 6)) * 128 + am) * 64 + ak;

  const int wid  = tid >> 6;
  const int lane = tid & 63;
  const int wm   = (wid & 1) * 64;
  const int wn   = (wid >> 1) * 64;
  const int lrow = lane & 15;
  const int lk   = (lane >> 4) * 8;

  f32x4 acc[4][4];
#pragma unroll
  for (int i = 0; i < 4; i++)
#pragma unroll
    for (int j = 0; j < 4; j++) acc[i][j] = (f32x4){0.f, 0.f, 0.f, 0.f};

  uint4 pa0, pa1, pa2, pa3, pb0, pb1, pb2, pb3;
  auto LOADT = [&](int kt) {
    const unsigned short* a = Ap + (size_t)kt * APITCH;
    const unsigned short* b = Bp + (size_t)kt * (128 * 64);
    pa0 = *(const uint4*)(a);      pa1 = *(const uint4*)(a + 8);
    pa2 = *(const uint4*)(a + 16); pa3 = *(const uint4*)(a + 24);
    pb0 = *(const uint4*)(b);      pb1 = *(const uint4*)(b + 8);
    pb2 = *(const uint4*)(b + 16); pb3 = *(const uint4*)(b + 24);
  };
  auto STORET = [&]() {
    unsigned short* as = &As[am * LDA2 + ak];
    unsigned short* bs = &Bs[am * LDA2 + ak];
    *(uint4*)(as)      = pa0; *(uint4*)(as + 8)  = pa1;
    *(uint4*)(as + 16) = pa2; *(uint4*)(as + 24) = pa3;
    *(uint4*)(bs)      = pb0; *(uint4*)(bs + 8)  = pb1;
    *(uint4*)(bs + 16) = pb2; *(uint4*)(bs + 24) = pb3;
  };

  LOADT(0);
  STORET();
  for (int kt = 0; kt < KITERS; kt++) {
    __syncthreads();
    if (kt + 1 < KITERS) LOADT(kt + 1);
#pragma unroll
    for (int ksb = 0; ksb < 2; ksb++) {
      bf16x8 af[4], bfr[4];
#pragma unroll
      for (int i = 0; i < 4; i++)
        af[i]  = *(const bf16x8*)&As[(wm + i * 16 + lrow) * LDA2 + ksb * 32 + lk];
#pragma unroll
      for (int j = 0; j < 4; j++)
        bfr[j] = *(const bf16x8*)&Bs[(wn + j * 16 + lrow) * LDA2 + ksb * 32 + lk];
#pragma unroll
      for (int i = 0; i < 4; i++)
#pragma unroll
        for (int j = 0; j < 4; j++)
          acc[i][j] = __builtin_amdgcn_mfma_f32_16x16x32_bf16(af[i], bfr[j], acc[i][j], 0, 0, 0);
    }
    __syncthreads();
    if (kt + 1 < KITERS) STORET();
  }

  // epilogue: C/D layout col=lane&15, row=(lane>>4)*4+reg
  const int crow = (lane >> 4) * 4;
  const int ccol = lane & 15;
  const size_t rbh = (size_t)(oe >> 7) + mt;
  float* yp = yout + (size_t)ks * ((size_t)YROWS * NCOLS);   // ks-partial buffer
#pragma unroll
  for (int j = 0; j < 4; j++) {
    const int gn = nt * BN + wn + j * 16 + ccol;
    const float bv = bias[e * NCOLS + gn];
#pragma unroll
    for (int i = 0; i < 4; i++) {
#pragma unroll
      for (int r = 0; r < 4; r++) {
        const int lm = wm + i * 16 + crow + r;
        float v = acc[i][j][r];
        if (PHASE == 1) {
          v += bv;
          v = v > 0.f ? v : 0.f;
          Hout[(((rbh * (NCOLS / 64) + (gn >> 6)) * 128 + lm) * 64) + (gn & 63)] = f2bf(v);
        } else {
          if (ks == 0) v += bv;
          yp[(size_t)(oe + mt * BM + lm) * NCOLS + gn] = v;   // plain store
        }
      }
    }
  }
}

// ======== v1 GEMM (fallback, f32 weights in-flight, row-major H, atomics) ========
template<int PHASE, int KTOT, int NCOLS, int KSPLIT>
__global__ __launch_bounds__(256) void moe_gemm_v1(
    const unsigned short* __restrict__ Asrc,
    const float* __restrict__ Wbase,
    const float* __restrict__ bias,
    const int* __restrict__ cntpad, const int* __restrict__ offs,
    const int* __restrict__ perm, const float* __restrict__ pw,
    unsigned short* __restrict__ Hout, float* __restrict__ out)
{
  const int e  = blockIdx.z;
  const int mt = blockIdx.y;
  const int nt = blockIdx.x / KSPLIT;
  const int ks = blockIdx.x % KSPLIT;
  const int cp = cntpad[e];
  if (mt * BM >= cp) return;
  const int tid = threadIdx.x;
  const int oe  = offs[e];

  __shared__ unsigned short As[BM * LDAV1];
  __shared__ unsigned short Bs[BN * LDAV1];

  const int am = tid >> 1;
  const int ak = (tid & 1) * 16;
  size_t arow_off;
  if (PHASE == 1) {
    int token = perm[e * T_TOK + mt * BM + am];
    arow_off = (size_t)token * KTOT;
  } else {
    arow_off = (size_t)(oe + mt * BM + am) * (size_t)KTOT;
  }
  const int bn  = tid & 127;
  const int bk0 = (tid >> 7) * 16;
  const float* Wexp = Wbase + (size_t)e * KTOT * NCOLS + (size_t)nt * BN;
  const int kbase0 = ks * (KTOT / KSPLIT);
  const int KITERS = (KTOT / KSPLIT) / 32;
  const int wid  = tid >> 6;
  const int lane = tid & 63;
  const int wm   = (wid & 1) * 64;
  const int wn   = (wid >> 1) * 64;
  const int lrow = lane & 15;
  const int lk   = (lane >> 4) * 8;

  f32x4 acc[4][4];
#pragma unroll
  for (int i = 0; i < 4; i++)
#pragma unroll
    for (int j = 0; j < 4; j++) acc[i][j] = (f32x4){0.f, 0.f, 0.f, 0.f};

  for (int kt = 0; kt < KITERS; kt++) {
    const int kb = kbase0 + kt * 32;
    {
      const unsigned short* src = Asrc + arow_off + kb + ak;
      uint4 v0 = *(const uint4*)(src);
      uint4 v1 = *(const uint4*)(src + 8);
      *(uint4*)&As[am * LDAV1 + ak]     = v0;
      *(uint4*)&As[am * LDAV1 + ak + 8] = v1;
    }
#pragma unroll
    for (int t2 = 0; t2 < 2; t2++) {
      const int kk = bk0 + t2 * 8;
      const float* wp = Wexp + (size_t)(kb + kk) * NCOLS + bn;
      ushort8 tv;
#pragma unroll
      for (int j = 0; j < 8; j++) tv[j] = f2bf(wp[(size_t)j * NCOLS]);
      *(ushort8*)&Bs[bn * LDAV1 + kk] = tv;
    }
    __syncthreads();
    bf16x8 af[4], bfr[4];
#pragma unroll
    for (int i = 0; i < 4; i++) af[i]  = *(const bf16x8*)&As[(wm + i * 16 + lrow) * LDAV1 + lk];
#pragma unroll
    for (int j = 0; j < 4; j++) bfr[j] = *(const bf16x8*)&Bs[(wn + j * 16 + lrow) * LDAV1 + lk];
#pragma unroll
    for (int i = 0; i < 4; i++)
#pragma unroll
      for (int j = 0; j < 4; j++)
        acc[i][j] = __builtin_amdgcn_mfma_f32_16x16x32_bf16(af[i], bfr[j], acc[i][j], 0, 0, 0);
    __syncthreads();
  }

  const int crow = (lane >> 4) * 4;
  const int ccol = lane & 15;
#pragma unroll
  for (int j = 0; j < 4; j++) {
    const int gn = nt * BN + wn + j * 16 + ccol;
    const float bv = bias[e * NCOLS + gn];
#pragma unroll
    for (int i = 0; i < 4; i++) {
#pragma unroll
      for (int r = 0; r < 4; r++) {
        const int lm = wm + i * 16 + crow + r;
        float v = acc[i][j][r];
        if (PHASE == 1) {
          v += bv;
          v = v > 0.f ? v : 0.f;
          Hout[(size_t)(oe + mt * BM + lm) * NCOLS + gn] = f2bf(v);
        } else {
          if (ks == 0) v += bv;
          const int li    = e * T_TOK + mt * BM + lm;
          const int token = perm[li];
          const float w   = pw[li];
          atomicAdd(&out[(size_t)token * NCOLS + gn], w * v);
        }
      }
    }
  }
}

extern "C" void kernel_launch(void* const* d_in, const int* in_sizes, int n_in,
                              void* d_out, int out_size, void* d_ws, size_t ws_size,
                              hipStream_t stream) {
  const float* x  = (const float*)d_in[0];
  const float* wg = (const float*)d_in[1];
  const float* bg = (const float*)d_in[2];
  const float* w1 = (const float*)d_in[3];
  const float* b1 = (const float*)d_in[4];
  const float* w2 = (const float*)d_in[5];
  const float* b2 = (const float*)d_in[6];
  float* out = (float*)d_out;

  // ---- workspace layout ----
  const size_t XB_BYTES   = (size_t)T_TOK * DM * 2;          // 4 MB
  const size_t PERM_BYTES = (size_t)NE * T_TOK * 4;          // 64 KB
  const size_t PW_BYTES   = (size_t)NE * T_TOK * 4;          // 64 KB
  const size_t TOK_BYTES  = (size_t)T_TOK * 2 * 4;           // 16 KB (x2)
  const size_t H_BYTES    = (size_t)(2 * T_TOK + NE * BM) * DF * 2;  // 40 MB (packed layout)
  const size_t W1T_BYTES  = (size_t)NE * DF * DM * 2;        // 64 MB
  const size_t W2T_BYTES  = (size_t)NE * DM * DF * 2;        // 64 MB

  char* wsp = (char*)d_ws;
  size_t off = 0;
  unsigned short* xb = (unsigned short*)(wsp + off); off += XB_BYTES;
  int*   cnt    = (int*)(wsp + off); off += 256;             // cnt/cntpad/offs packed
  int*   cntpad = cnt + 8;
  int*   offs   = cnt + 16;
  int*   perm   = (int*)(wsp + off);   off += PERM_BYTES;
  float* pwt    = (float*)(wsp + off); off += PW_BYTES;
  int*   tok2slot = (int*)(wsp + off);   off += TOK_BYTES;
  float* tokw     = (float*)(wsp + off); off += TOK_BYTES;
  unsigned short* H   = (unsigned short*)(wsp + off); off += H_BYTES;
  unsigned short* w1t = (unsigned short*)(wsp + off); off += W1T_BYTES;
  unsigned short* w2t = (unsigned short*)(wsp + off); off += W2T_BYTES;
  const size_t REQUIRED = off;

  // y partials alias w1t (dead after phase 1): 2 buffers x YROWS x DM f32 = 40 MB <= 64 MB
  float* y = (float*)w1t;

  hipMemsetAsync(cnt, 0, 256, stream);
  hipMemsetAsync(d_out, 0, (size_t)T_TOK * DM * 4, stream);   // needed only for v1 fallback

  convert_x_kernel<<<(T_TOK * DM / 8) / 256, 256, 0, stream>>>(x, xb);
  gating_kernel<<<T_TOK / 4, 256, 0, stream>>>(x, wg, bg, cnt, perm, pwt, tok2slot, tokw);
  pad_scan_kernel<<<1, 256, 0, stream>>>(cnt, cntpad, offs, perm, pwt);

  if (ws_size >= REQUIRED) {
    // convert + tile-pack weights to bf16 [e][nt][kt][128][64]
    transpose_convert_packed<DM, DF><<<dim3(DF / 128, DM / 64, NE), 256, 0, stream>>>(w1, w1t);
    transpose_convert_packed<DF, DM><<<dim3(DM / 128, DF / 64, NE), 256, 0, stream>>>(w2, w2t);

    moe_gemm5<1, DM, DF, 1><<<dim3(DF / BN, T_TOK / BM, NE), 256, 0, stream>>>(
        xb, w1t, b1, cntpad, offs, perm, H, nullptr);
    // phase 2: plain stores into y[ks] (aliases w1t, which is dead now)
    moe_gemm5<2, DF, DM, 2><<<dim3((DM / BN) * 2, T_TOK / BM, NE), 256, 0, stream>>>(
        H, w2t, b2, cntpad, offs, perm, nullptr, y);
    combine_kernel<<<T_TOK, 256, 0, stream>>>(
        y, y + (size_t)YROWS * DM, offs, tok2slot, tokw, out);
  } else {
    // fallback: v1 path (needs only ~46 MB of ws), row-major H, atomic combine
    moe_gemm_v1<1, DM, DF, 1><<<dim3(DF / BN, T_TOK / BM, NE), 256, 0, stream>>>(
        xb, w1, b1, cntpad, offs, perm, pwt, H, nullptr);
    moe_gemm_v1<2, DF, DM, 4><<<dim3((DM / BN) * 4, T_TOK / BM, NE), 256, 0, stream>>>(
        H, w2, b2, cntpad, offs, perm, pwt, nullptr, out);
  }
}

// Round 4
// 513.932 us; speedup vs baseline: 1.4264x; 1.0036x over previous
//
#include <hip/hip_runtime.h>
#include <hip/hip_bf16.h>
#include <math.h>

#define T_TOK 2048
#define DM    1024
#define DF    4096
#define NE    8
#define BM    128
#define BN    128
#define BK    64
#define LDA2  72   // LDS row stride (144B): rows 8 apart alias 2-way (free), b128-aligned
#define LDAV1 40   // v1 fallback LDS stride
#define YROWS 5120 // max padded rows (4096 + 8*127 rounded up)

typedef __attribute__((ext_vector_type(8))) short          bf16x8;
typedef __attribute__((ext_vector_type(8))) unsigned short ushort8;
typedef __attribute__((ext_vector_type(4))) float          f32x4;

__device__ __forceinline__ unsigned short f2bf(float f) {
  unsigned u = __builtin_bit_cast(unsigned, f);
  unsigned r = u + 0x7fffu + ((u >> 16) & 1u);   // RNE
  return (unsigned short)(r >> 16);
}

// ---------------- x f32 -> bf16 ----------------
__global__ void convert_x_kernel(const float* __restrict__ x, unsigned short* __restrict__ xb) {
  int i = blockIdx.x * blockDim.x + threadIdx.x;   // one thread per 8 elements
  const float* src = x + (size_t)i * 8;
  float4 a = *(const float4*)(src);
  float4 b = *(const float4*)(src + 4);
  ushort8 v;
  v[0] = f2bf(a.x); v[1] = f2bf(a.y); v[2] = f2bf(a.z); v[3] = f2bf(a.w);
  v[4] = f2bf(b.x); v[5] = f2bf(b.y); v[6] = f2bf(b.z); v[7] = f2bf(b.w);
  *(ushort8*)(xb + (size_t)i * 8) = v;
}

// ---------------- weight convert + TILE-PACK (COALESCED stores) ----------------
// W[E][K][N] f32 -> Wt[e][n/128][k/64][128][64] bf16. Output tile contiguous (16 KB).
// Store map: c = tid&7 (k-chunk of 8), n = (tid>>3) + 32p -> consecutive tids write
// consecutive 16-B chunks (full 128-B runs per 8 lanes; 4-KB linear per pass).
template<int K, int N>
__device__ __forceinline__ void transpose_tile(
    float (*Ls)[129], const float* __restrict__ W, unsigned short* __restrict__ Wt,
    int e, int kt, int nt, int tid)
{
  const int k0 = kt * 64;
  const int n0 = nt * 128;
  const float* Wp = W + (size_t)e * K * N;
  {  // load 64k x 128n tile, float4-coalesced
    const int kl = tid >> 5;            // 0..7
    const int nl = (tid & 31) * 4;
#pragma unroll
    for (int p = 0; p < 8; p++) {
      const int k = kl + p * 8;
      float4 v = *(const float4*)(Wp + (size_t)(k0 + k) * N + n0 + nl);
      Ls[k][nl + 0] = v.x; Ls[k][nl + 1] = v.y; Ls[k][nl + 2] = v.z; Ls[k][nl + 3] = v.w;
    }
  }
  __syncthreads();
  unsigned short* Wo = Wt + ((((size_t)e * (N / 128) + nt) * (K / 64) + kt) * 128) * 64;
  {
    const int c  = tid & 7;             // k-chunk (8 elems)
    const int nb = tid >> 3;            // 0..31
#pragma unroll
    for (int p = 0; p < 4; p++) {
      const int n = nb + p * 32;
      ushort8 o;
#pragma unroll
      for (int j = 0; j < 8; j++) o[j] = f2bf(Ls[c * 8 + j][n]);   // 2-way bank alias (free)
      *(ushort8*)(Wo + (size_t)n * 64 + c * 8) = o;                // coalesced
    }
  }
}

// one launch does BOTH weight tensors: blocks [0,4096) = w1, [4096,8192) = w2
__global__ __launch_bounds__(256) void transpose_both(
    const float* __restrict__ w1, const float* __restrict__ w2,
    unsigned short* __restrict__ w1t, unsigned short* __restrict__ w2t)
{
  __shared__ float Ls[64][129];
  const int tid = threadIdx.x;
  int b = blockIdx.x;
  if (b < 4096) {          // w1: K=DM=1024 (16 kt), N=DF=4096 (32 nt)
    const int nt = b & 31;
    const int kt = (b >> 5) & 15;
    const int e  = b >> 9;
    transpose_tile<DM, DF>(Ls, w1, w1t, e, kt, nt, tid);
  } else {                 // w2: K=DF=4096 (64 kt), N=DM=1024 (8 nt)
    b -= 4096;
    const int nt = b & 7;
    const int kt = (b >> 3) & 63;
    const int e  = b >> 9;
    transpose_tile<DF, DM>(Ls, w2, w2t, e, kt, nt, tid);
  }
}

// ---------------- gating: one wave per token ----------------
__global__ __launch_bounds__(256) void gating_kernel(
    const float* __restrict__ x, const float* __restrict__ wg, const float* __restrict__ bg,
    int* __restrict__ cnt, int* __restrict__ perm, float* __restrict__ pw,
    int* __restrict__ tok2slot, float* __restrict__ tokw)
{
  int wid  = (blockIdx.x * blockDim.x + threadIdx.x) >> 6;   // token
  int lane = threadIdx.x & 63;
  if (wid >= T_TOK) return;
  const float* xr = x + (size_t)wid * DM;

  float acc[NE];
#pragma unroll
  for (int e = 0; e < NE; e++) acc[e] = 0.f;

  for (int d = lane; d < DM; d += 64) {
    float xv = xr[d];
    const float* wr = wg + (size_t)d * NE;
#pragma unroll
    for (int e = 0; e < NE; e++) acc[e] += xv * wr[e];
  }
#pragma unroll
  for (int off = 32; off > 0; off >>= 1) {
#pragma unroll
    for (int e = 0; e < NE; e++) acc[e] += __shfl_xor(acc[e], off, 64);
  }
  if (lane == 0) {
    float v[NE];
#pragma unroll
    for (int e = 0; e < NE; e++) v[e] = acc[e] + bg[e];
    int i0 = 0; float v0 = v[0];
#pragma unroll
    for (int e = 1; e < NE; e++) { if (v[e] > v0) { v0 = v[e]; i0 = e; } }
    int i1 = -1; float v1 = -INFINITY;
#pragma unroll
    for (int e = 0; e < NE; e++) { if (e != i0 && v[e] > v1) { v1 = v[e]; i1 = e; } }
    float e1 = expf(v1 - v0);
    float s  = 1.f + e1;
    float w0 = 1.f / s, w1 = e1 / s;
    int p0 = atomicAdd(&cnt[i0], 1);
    perm[i0 * T_TOK + p0] = wid; pw[i0 * T_TOK + p0] = w0;
    int p1 = atomicAdd(&cnt[i1], 1);
    perm[i1 * T_TOK + p1] = wid; pw[i1 * T_TOK + p1] = w1;
    tok2slot[2 * wid + 0] = (i0 << 16) | p0;  tokw[2 * wid + 0] = w0;
    tok2slot[2 * wid + 1] = (i1 << 16) | p1;  tokw[2 * wid + 1] = w1;
  }
}

// ---------------- pad lists to BM multiple + exclusive scan ----------------
__global__ void pad_scan_kernel(const int* __restrict__ cnt, int* __restrict__ cntpad,
                                int* __restrict__ offs, int* __restrict__ perm, float* __restrict__ pw)
{
  if (threadIdx.x == 0) {
    int o = 0;
    for (int e = 0; e < NE; e++) {
      int c  = cnt[e];
      int cp = (c + BM - 1) / BM * BM;
      cntpad[e] = cp;
      offs[e]   = o;
      o += cp;
    }
    offs[NE] = o;
  }
  for (int e = 0; e < NE; e++) {
    int c  = cnt[e];
    int cp = (c + BM - 1) / BM * BM;
    for (int i = c + threadIdx.x; i < cp; i += blockDim.x) {
      perm[e * T_TOK + i] = 0;
      pw[e * T_TOK + i]   = 0.f;
    }
  }
}

// ---------------- atomic-free combine: out[t] = sum_s w_s * (y0[row_s] + y1[row_s]) ----------------
__global__ __launch_bounds__(256) void combine_kernel(
    const float* __restrict__ y0, const float* __restrict__ y1,
    const int* __restrict__ offs, const int* __restrict__ tok2slot,
    const float* __restrict__ tokw, float* __restrict__ out)
{
  const int t = blockIdx.x;
  const int d = threadIdx.x * 4;
  const int s0 = tok2slot[2 * t + 0];
  const int s1 = tok2slot[2 * t + 1];
  const float w0 = tokw[2 * t + 0];
  const float w1 = tokw[2 * t + 1];
  const size_t r0 = (size_t)(offs[s0 >> 16] + (s0 & 0xffff)) * DM + d;
  const size_t r1 = (size_t)(offs[s1 >> 16] + (s1 & 0xffff)) * DM + d;
  float4 a0 = *(const float4*)(y0 + r0);
  float4 b0 = *(const float4*)(y1 + r0);
  float4 a1 = *(const float4*)(y0 + r1);
  float4 b1 = *(const float4*)(y1 + r1);
  float4 o;
  o.x = w0 * (a0.x + b0.x) + w1 * (a1.x + b1.x);
  o.y = w0 * (a0.y + b0.y) + w1 * (a1.y + b1.y);
  o.z = w0 * (a0.z + b0.z) + w1 * (a1.z + b1.z);
  o.w = w0 * (a0.w + b0.w) + w1 * (a1.w + b1.w);
  *(float4*)(out + (size_t)t * DM + d) = o;
}

// ======== v5 GEMM (FROZEN from round 3): BK=64, tile-packed operands, depth-1 reg prefetch ========
// PHASE 1: H = relu(X_e * W1 + b1), H stored TILE-PACKED [rb][kt][128][64]
// PHASE 2: y[ks][row] = H_e * W2 (+ b2 if ks==0) -- PLAIN f32 stores, no atomics
template<int PHASE, int KTOT, int NCOLS, int KSPLIT>
__global__ __launch_bounds__(256, 3) void moe_gemm5(
    const unsigned short* __restrict__ Asrc,
    const unsigned short* __restrict__ Bt,
    const float* __restrict__ bias,
    const int* __restrict__ cntpad, const int* __restrict__ offs,
    const int* __restrict__ perm,
    unsigned short* __restrict__ Hout, float* __restrict__ yout)
{
  const int e  = blockIdx.z;
  const int mt = blockIdx.y;
  const int nt = blockIdx.x / KSPLIT;
  const int ks = blockIdx.x % KSPLIT;
  const int cp = cntpad[e];
  if (mt * BM >= cp) return;
  const int tid = threadIdx.x;
  const int oe  = offs[e];

  __shared__ unsigned short As[BM * LDA2];
  __shared__ unsigned short Bs[BN * LDA2];

  const int am = tid >> 1;
  const int ak = (tid & 1) * 32;
  const int kb0 = ks * (KTOT / KSPLIT);
  const int KITERS = (KTOT / KSPLIT) / BK;

  const unsigned short* Ap;
  size_t APITCH;
  if (PHASE == 1) {
    int token = perm[e * T_TOK + mt * BM + am];
    Ap = Asrc + (size_t)token * KTOT + kb0 + ak;
    APITCH = BK;
  } else {
    const size_t rb = (size_t)(oe >> 7) + mt;        // H row-block (oe is 128-multiple)
    Ap = Asrc + (((rb * (KTOT / 64) + (kb0 >> 6)) * 128 + am) * 64) + ak;
    APITCH = (size_t)128 * 64;
  }
  const unsigned short* Bp =
      Bt + ((((size_t)e * (NCOLS / 128) + nt) * (KTOT / 64) + (kb0 >> 6)) * 128 + am) * 64 + ak;

  const int wid  = tid >> 6;
  const int lane = tid & 63;
  const int wm   = (wid & 1) * 64;
  const int wn   = (wid >> 1) * 64;
  const int lrow = lane & 15;
  const int lk   = (lane >> 4) * 8;

  f32x4 acc[4][4];
#pragma unroll
  for (int i = 0; i < 4; i++)
#pragma unroll
    for (int j = 0; j < 4; j++) acc[i][j] = (f32x4){0.f, 0.f, 0.f, 0.f};

  uint4 pa0, pa1, pa2, pa3, pb0, pb1, pb2, pb3;
  auto LOADT = [&](int kt) {
    const unsigned short* a = Ap + (size_t)kt * APITCH;
    const unsigned short* b = Bp + (size_t)kt * (128 * 64);
    pa0 = *(const uint4*)(a);      pa1 = *(const uint4*)(a + 8);
    pa2 = *(const uint4*)(a + 16); pa3 = *(const uint4*)(a + 24);
    pb0 = *(const uint4*)(b);      pb1 = *(const uint4*)(b + 8);
    pb2 = *(const uint4*)(b + 16); pb3 = *(const uint4*)(b + 24);
  };
  auto STORET = [&]() {
    unsigned short* as = &As[am * LDA2 + ak];
    unsigned short* bs = &Bs[am * LDA2 + ak];
    *(uint4*)(as)      = pa0; *(uint4*)(as + 8)  = pa1;
    *(uint4*)(as + 16) = pa2; *(uint4*)(as + 24) = pa3;
    *(uint4*)(bs)      = pb0; *(uint4*)(bs + 8)  = pb1;
    *(uint4*)(bs + 16) = pb2; *(uint4*)(bs + 24) = pb3;
  };

  LOADT(0);
  STORET();
  for (int kt = 0; kt < KITERS; kt++) {
    __syncthreads();
    if (kt + 1 < KITERS) LOADT(kt + 1);
#pragma unroll
    for (int ksb = 0; ksb < 2; ksb++) {
      bf16x8 af[4], bfr[4];
#pragma unroll
      for (int i = 0; i < 4; i++)
        af[i]  = *(const bf16x8*)&As[(wm + i * 16 + lrow) * LDA2 + ksb * 32 + lk];
#pragma unroll
      for (int j = 0; j < 4; j++)
        bfr[j] = *(const bf16x8*)&Bs[(wn + j * 16 + lrow) * LDA2 + ksb * 32 + lk];
#pragma unroll
      for (int i = 0; i < 4; i++)
#pragma unroll
        for (int j = 0; j < 4; j++)
          acc[i][j] = __builtin_amdgcn_mfma_f32_16x16x32_bf16(af[i], bfr[j], acc[i][j], 0, 0, 0);
    }
    __syncthreads();
    if (kt + 1 < KITERS) STORET();
  }

  // epilogue: C/D layout col=lane&15, row=(lane>>4)*4+reg
  const int crow = (lane >> 4) * 4;
  const int ccol = lane & 15;
  const size_t rbh = (size_t)(oe >> 7) + mt;
  float* yp = yout + (size_t)ks * ((size_t)YROWS * NCOLS);   // ks-partial buffer
#pragma unroll
  for (int j = 0; j < 4; j++) {
    const int gn = nt * BN + wn + j * 16 + ccol;
    const float bv = bias[e * NCOLS + gn];
#pragma unroll
    for (int i = 0; i < 4; i++) {
#pragma unroll
      for (int r = 0; r < 4; r++) {
        const int lm = wm + i * 16 + crow + r;
        float v = acc[i][j][r];
        if (PHASE == 1) {
          v += bv;
          v = v > 0.f ? v : 0.f;
          Hout[(((rbh * (NCOLS / 64) + (gn >> 6)) * 128 + lm) * 64) + (gn & 63)] = f2bf(v);
        } else {
          if (ks == 0) v += bv;
          yp[(size_t)(oe + mt * BM + lm) * NCOLS + gn] = v;   // plain store
        }
      }
    }
  }
}

// ======== v1 GEMM (fallback, f32 weights in-flight, row-major H, atomics) ========
template<int PHASE, int KTOT, int NCOLS, int KSPLIT>
__global__ __launch_bounds__(256) void moe_gemm_v1(
    const unsigned short* __restrict__ Asrc,
    const float* __restrict__ Wbase,
    const float* __restrict__ bias,
    const int* __restrict__ cntpad, const int* __restrict__ offs,
    const int* __restrict__ perm, const float* __restrict__ pw,
    unsigned short* __restrict__ Hout, float* __restrict__ out)
{
  const int e  = blockIdx.z;
  const int mt = blockIdx.y;
  const int nt = blockIdx.x / KSPLIT;
  const int ks = blockIdx.x % KSPLIT;
  const int cp = cntpad[e];
  if (mt * BM >= cp) return;
  const int tid = threadIdx.x;
  const int oe  = offs[e];

  __shared__ unsigned short As[BM * LDAV1];
  __shared__ unsigned short Bs[BN * LDAV1];

  const int am = tid >> 1;
  const int ak = (tid & 1) * 16;
  size_t arow_off;
  if (PHASE == 1) {
    int token = perm[e * T_TOK + mt * BM + am];
    arow_off = (size_t)token * KTOT;
  } else {
    arow_off = (size_t)(oe + mt * BM + am) * (size_t)KTOT;
  }
  const int bn  = tid & 127;
  const int bk0 = (tid >> 7) * 16;
  const float* Wexp = Wbase + (size_t)e * KTOT * NCOLS + (size_t)nt * BN;
  const int kbase0 = ks * (KTOT / KSPLIT);
  const int KITERS = (KTOT / KSPLIT) / 32;
  const int wid  = tid >> 6;
  const int lane = tid & 63;
  const int wm   = (wid & 1) * 64;
  const int wn   = (wid >> 1) * 64;
  const int lrow = lane & 15;
  const int lk   = (lane >> 4) * 8;

  f32x4 acc[4][4];
#pragma unroll
  for (int i = 0; i < 4; i++)
#pragma unroll
    for (int j = 0; j < 4; j++) acc[i][j] = (f32x4){0.f, 0.f, 0.f, 0.f};

  for (int kt = 0; kt < KITERS; kt++) {
    const int kb = kbase0 + kt * 32;
    {
      const unsigned short* src = Asrc + arow_off + kb + ak;
      uint4 v0 = *(const uint4*)(src);
      uint4 v1 = *(const uint4*)(src + 8);
      *(uint4*)&As[am * LDAV1 + ak]     = v0;
      *(uint4*)&As[am * LDAV1 + ak + 8] = v1;
    }
#pragma unroll
    for (int t2 = 0; t2 < 2; t2++) {
      const int kk = bk0 + t2 * 8;
      const float* wp = Wexp + (size_t)(kb + kk) * NCOLS + bn;
      ushort8 tv;
#pragma unroll
      for (int j = 0; j < 8; j++) tv[j] = f2bf(wp[(size_t)j * NCOLS]);
      *(ushort8*)&Bs[bn * LDAV1 + kk] = tv;
    }
    __syncthreads();
    bf16x8 af[4], bfr[4];
#pragma unroll
    for (int i = 0; i < 4; i++) af[i]  = *(const bf16x8*)&As[(wm + i * 16 + lrow) * LDAV1 + lk];
#pragma unroll
    for (int j = 0; j < 4; j++) bfr[j] = *(const bf16x8*)&Bs[(wn + j * 16 + lrow) * LDAV1 + lk];
#pragma unroll
    for (int i = 0; i < 4; i++)
#pragma unroll
      for (int j = 0; j < 4; j++)
        acc[i][j] = __builtin_amdgcn_mfma_f32_16x16x32_bf16(af[i], bfr[j], acc[i][j], 0, 0, 0);
    __syncthreads();
  }

  const int crow = (lane >> 4) * 4;
  const int ccol = lane & 15;
#pragma unroll
  for (int j = 0; j < 4; j++) {
    const int gn = nt * BN + wn + j * 16 + ccol;
    const float bv = bias[e * NCOLS + gn];
#pragma unroll
    for (int i = 0; i < 4; i++) {
#pragma unroll
      for (int r = 0; r < 4; r++) {
        const int lm = wm + i * 16 + crow + r;
        float v = acc[i][j][r];
        if (PHASE == 1) {
          v += bv;
          v = v > 0.f ? v : 0.f;
          Hout[(size_t)(oe + mt * BM + lm) * NCOLS + gn] = f2bf(v);
        } else {
          if (ks == 0) v += bv;
          const int li    = e * T_TOK + mt * BM + lm;
          const int token = perm[li];
          const float w   = pw[li];
          atomicAdd(&out[(size_t)token * NCOLS + gn], w * v);
        }
      }
    }
  }
}

extern "C" void kernel_launch(void* const* d_in, const int* in_sizes, int n_in,
                              void* d_out, int out_size, void* d_ws, size_t ws_size,
                              hipStream_t stream) {
  const float* x  = (const float*)d_in[0];
  const float* wg = (const float*)d_in[1];
  const float* bg = (const float*)d_in[2];
  const float* w1 = (const float*)d_in[3];
  const float* b1 = (const float*)d_in[4];
  const float* w2 = (const float*)d_in[5];
  const float* b2 = (const float*)d_in[6];
  float* out = (float*)d_out;

  // ---- workspace layout ----
  const size_t XB_BYTES   = (size_t)T_TOK * DM * 2;          // 4 MB
  const size_t PERM_BYTES = (size_t)NE * T_TOK * 4;          // 64 KB
  const size_t PW_BYTES   = (size_t)NE * T_TOK * 4;          // 64 KB
  const size_t TOK_BYTES  = (size_t)T_TOK * 2 * 4;           // 16 KB (x2)
  const size_t H_BYTES    = (size_t)(2 * T_TOK + NE * BM) * DF * 2;  // 40 MB (packed layout)
  const size_t W1T_BYTES  = (size_t)NE * DF * DM * 2;        // 64 MB
  const size_t W2T_BYTES  = (size_t)NE * DM * DF * 2;        // 64 MB

  char* wsp = (char*)d_ws;
  size_t off = 0;
  unsigned short* xb = (unsigned short*)(wsp + off); off += XB_BYTES;
  int*   cnt    = (int*)(wsp + off); off += 256;             // cnt/cntpad/offs packed
  int*   cntpad = cnt + 8;
  int*   offs   = cnt + 16;
  int*   perm   = (int*)(wsp + off);   off += PERM_BYTES;
  float* pwt    = (float*)(wsp + off); off += PW_BYTES;
  int*   tok2slot = (int*)(wsp + off);   off += TOK_BYTES;
  float* tokw     = (float*)(wsp + off); off += TOK_BYTES;
  unsigned short* H   = (unsigned short*)(wsp + off); off += H_BYTES;
  unsigned short* w1t = (unsigned short*)(wsp + off); off += W1T_BYTES;
  unsigned short* w2t = (unsigned short*)(wsp + off); off += W2T_BYTES;
  const size_t REQUIRED = off;

  // y partials alias w1t (dead after phase 1): 2 buffers x YROWS x DM f32 = 40 MB <= 64 MB
  float* y = (float*)w1t;

  hipMemsetAsync(cnt, 0, 256, stream);

  convert_x_kernel<<<(T_TOK * DM / 8) / 256, 256, 0, stream>>>(x, xb);
  gating_kernel<<<T_TOK / 4, 256, 0, stream>>>(x, wg, bg, cnt, perm, pwt, tok2slot, tokw);
  pad_scan_kernel<<<1, 256, 0, stream>>>(cnt, cntpad, offs, perm, pwt);

  if (ws_size >= REQUIRED) {
    // convert + tile-pack BOTH weight tensors in one launch (coalesced stores)
    transpose_both<<<8192, 256, 0, stream>>>(w1, w2, w1t, w2t);

    moe_gemm5<1, DM, DF, 1><<<dim3(DF / BN, T_TOK / BM, NE), 256, 0, stream>>>(
        xb, w1t, b1, cntpad, offs, perm, H, nullptr);
    // phase 2: plain stores into y[ks] (aliases w1t, which is dead now)
    moe_gemm5<2, DF, DM, 2><<<dim3((DM / BN) * 2, T_TOK / BM, NE), 256, 0, stream>>>(
        H, w2t, b2, cntpad, offs, perm, nullptr, y);
    combine_kernel<<<T_TOK, 256, 0, stream>>>(
        y, y + (size_t)YROWS * DM, offs, tok2slot, tokw, out);
  } else {
    // fallback: v1 path (needs only ~46 MB of ws), row-major H, atomic combine
    hipMemsetAsync(d_out, 0, (size_t)T_TOK * DM * 4, stream);
    moe_gemm_v1<1, DM, DF, 1><<<dim3(DF / BN, T_TOK / BM, NE), 256, 0, stream>>>(
        xb, w1, b1, cntpad, offs, perm, pwt, H, nullptr);
    moe_gemm_v1<2, DF, DM, 4><<<dim3((DM / BN) * 4, T_TOK / BM, NE), 256, 0, stream>>>(
        H, w2, b2, cntpad, offs, perm, pwt, nullptr, out);
  }
}

// Round 5
// 509.757 us; speedup vs baseline: 1.4380x; 1.0082x over previous
//
#include <hip/hip_runtime.h>
#include <hip/hip_bf16.h>
#include <math.h>

#define T_TOK 2048
#define DM    1024
#define DF    4096
#define NE    8
#define BM    128
#define BN    128
#define BK    64
#define LDA2  72   // GEMM LDS row stride (144B): rows 8 apart alias 2-way (free), b128-aligned
#define LDAV1 40   // v1 fallback LDS stride
#define YROWS 5120 // max padded rows (4096 + 8*127 rounded up)

typedef __attribute__((ext_vector_type(8))) short          bf16x8;
typedef __attribute__((ext_vector_type(8))) unsigned short ushort8;
typedef __attribute__((ext_vector_type(4))) float          f32x4;

__device__ __forceinline__ unsigned short f2bf(float f) {
  unsigned u = __builtin_bit_cast(unsigned, f);
  unsigned r = u + 0x7fffu + ((u >> 16) & 1u);   // RNE
  return (unsigned short)(r >> 16);
}

// ---------------- x f32 -> bf16 (fallback path only; fast path folds this into prep_all) ----
__global__ void convert_x_kernel(const float* __restrict__ x, unsigned short* __restrict__ xb) {
  int i = blockIdx.x * blockDim.x + threadIdx.x;   // one thread per 8 elements
  const float* src = x + (size_t)i * 8;
  float4 a = *(const float4*)(src);
  float4 b = *(const float4*)(src + 4);
  ushort8 v;
  v[0] = f2bf(a.x); v[1] = f2bf(a.y); v[2] = f2bf(a.z); v[3] = f2bf(a.w);
  v[4] = f2bf(b.x); v[5] = f2bf(b.y); v[6] = f2bf(b.z); v[7] = f2bf(b.w);
  *(ushort8*)(xb + (size_t)i * 8) = v;
}

// ---------------- prep_all: weight convert+tile-pack (32k x 128n tiles) + x convert ------------
// Blocks [0,8192): w1 tiles; [8192,16384): w2 tiles; [16384,17408): x convert.
// 16.5 KB LDS -> 8 blocks/CU (full occupancy) so load-phase of some blocks overlaps
// readout-phase of others. 4 independent float4 loads issued before any LDS store.
// Output layout: Wt[e][n/128][k/64][128][64] bf16 (each 32-k block fills one k-half).
__global__ __launch_bounds__(256, 8) void prep_all(
    const float* __restrict__ x, unsigned short* __restrict__ xb,
    const float* __restrict__ w1, const float* __restrict__ w2,
    unsigned short* __restrict__ w1t, unsigned short* __restrict__ w2t)
{
  __shared__ float Ls[32][129];
  const int tid = threadIdx.x;
  const int b = blockIdx.x;

  if (b >= 16384) {           // ---- x convert: 1024 blocks, one thread per 8 elements ----
    const int i = (b - 16384) * 256 + tid;
    const float* src = x + (size_t)i * 8;
    float4 a  = *(const float4*)(src);
    float4 c4 = *(const float4*)(src + 4);
    ushort8 v;
    v[0] = f2bf(a.x);  v[1] = f2bf(a.y);  v[2] = f2bf(a.z);  v[3] = f2bf(a.w);
    v[4] = f2bf(c4.x); v[5] = f2bf(c4.y); v[6] = f2bf(c4.z); v[7] = f2bf(c4.w);
    *(ushort8*)(xb + (size_t)i * 8) = v;
    return;
  }

  const float* W; unsigned short* Wt; int K, N, nt, kt32, e;
  if (b < 8192) {             // w1: K=DM (32 kt32), N=DF (32 nt)
    W = w1; Wt = w1t; K = DM; N = DF;
    nt = b & 31; kt32 = (b >> 5) & 31; e = b >> 10;
  } else {                    // w2: K=DF (128 kt32), N=DM (8 nt)
    const int b2 = b - 8192;
    W = w2; Wt = w2t; K = DF; N = DM;
    nt = b2 & 7; kt32 = (b2 >> 3) & 127; e = b2 >> 10;
  }

  // ---- load 32k x 128n f32 tile: 4 INDEPENDENT float4 loads, then LDS stores ----
  const float* Wp = W + (size_t)e * K * N + (size_t)(kt32 * 32) * N + nt * 128;
  const int kl = tid >> 5;            // 0..7
  const int nl = (tid & 31) * 4;
  float4 v0 = *(const float4*)(Wp + (size_t)(kl +  0) * N + nl);
  float4 v1 = *(const float4*)(Wp + (size_t)(kl +  8) * N + nl);
  float4 v2 = *(const float4*)(Wp + (size_t)(kl + 16) * N + nl);
  float4 v3 = *(const float4*)(Wp + (size_t)(kl + 24) * N + nl);
  Ls[kl +  0][nl + 0] = v0.x; Ls[kl +  0][nl + 1] = v0.y; Ls[kl +  0][nl + 2] = v0.z; Ls[kl +  0][nl + 3] = v0.w;
  Ls[kl +  8][nl + 0] = v1.x; Ls[kl +  8][nl + 1] = v1.y; Ls[kl +  8][nl + 2] = v1.z; Ls[kl +  8][nl + 3] = v1.w;
  Ls[kl + 16][nl + 0] = v2.x; Ls[kl + 16][nl + 1] = v2.y; Ls[kl + 16][nl + 2] = v2.z; Ls[kl + 16][nl + 3] = v2.w;
  Ls[kl + 24][nl + 0] = v3.x; Ls[kl + 24][nl + 1] = v3.y; Ls[kl + 24][nl + 2] = v3.z; Ls[kl + 24][nl + 3] = v3.w;
  __syncthreads();

  // ---- readout: thread = (c = 8-k chunk, n) ; 2-way LDS bank alias (free) ----
  unsigned short* Wo = Wt
      + ((((size_t)e * (N >> 7) + nt) * (K >> 6) + (kt32 >> 1)) * 128) * 64
      + (kt32 & 1) * 32;
  const int c  = tid & 3;             // k-chunk of 8 within the 32-k half
  const int nb = tid >> 2;            // 0..63
#pragma unroll
  for (int p = 0; p < 2; p++) {
    const int n = nb + p * 64;
    ushort8 o;
#pragma unroll
    for (int j = 0; j < 8; j++) o[j] = f2bf(Ls[c * 8 + j][n]);
    *(ushort8*)(Wo + (size_t)n * 64 + c * 8) = o;
  }
}

// ---------------- gating: one wave per token ----------------
__global__ __launch_bounds__(256) void gating_kernel(
    const float* __restrict__ x, const float* __restrict__ wg, const float* __restrict__ bg,
    int* __restrict__ cnt, int* __restrict__ perm, float* __restrict__ pw,
    int* __restrict__ tok2slot, float* __restrict__ tokw)
{
  int wid  = (blockIdx.x * blockDim.x + threadIdx.x) >> 6;   // token
  int lane = threadIdx.x & 63;
  if (wid >= T_TOK) return;
  const float* xr = x + (size_t)wid * DM;

  float acc[NE];
#pragma unroll
  for (int e = 0; e < NE; e++) acc[e] = 0.f;

  for (int d = lane; d < DM; d += 64) {
    float xv = xr[d];
    const float* wr = wg + (size_t)d * NE;
#pragma unroll
    for (int e = 0; e < NE; e++) acc[e] += xv * wr[e];
  }
#pragma unroll
  for (int off = 32; off > 0; off >>= 1) {
#pragma unroll
    for (int e = 0; e < NE; e++) acc[e] += __shfl_xor(acc[e], off, 64);
  }
  if (lane == 0) {
    float v[NE];
#pragma unroll
    for (int e = 0; e < NE; e++) v[e] = acc[e] + bg[e];
    int i0 = 0; float v0 = v[0];
#pragma unroll
    for (int e = 1; e < NE; e++) { if (v[e] > v0) { v0 = v[e]; i0 = e; } }
    int i1 = -1; float v1 = -INFINITY;
#pragma unroll
    for (int e = 0; e < NE; e++) { if (e != i0 && v[e] > v1) { v1 = v[e]; i1 = e; } }
    float e1 = expf(v1 - v0);
    float s  = 1.f + e1;
    float w0 = 1.f / s, w1 = e1 / s;
    int p0 = atomicAdd(&cnt[i0], 1);
    perm[i0 * T_TOK + p0] = wid; pw[i0 * T_TOK + p0] = w0;
    int p1 = atomicAdd(&cnt[i1], 1);
    perm[i1 * T_TOK + p1] = wid; pw[i1 * T_TOK + p1] = w1;
    tok2slot[2 * wid + 0] = (i0 << 16) | p0;  tokw[2 * wid + 0] = w0;
    tok2slot[2 * wid + 1] = (i1 << 16) | p1;  tokw[2 * wid + 1] = w1;
  }
}

// ---------------- pad lists to BM multiple + exclusive scan ----------------
__global__ void pad_scan_kernel(const int* __restrict__ cnt, int* __restrict__ cntpad,
                                int* __restrict__ offs, int* __restrict__ perm, float* __restrict__ pw)
{
  if (threadIdx.x == 0) {
    int o = 0;
    for (int e = 0; e < NE; e++) {
      int c  = cnt[e];
      int cp = (c + BM - 1) / BM * BM;
      cntpad[e] = cp;
      offs[e]   = o;
      o += cp;
    }
    offs[NE] = o;
  }
  for (int e = 0; e < NE; e++) {
    int c  = cnt[e];
    int cp = (c + BM - 1) / BM * BM;
    for (int i = c + threadIdx.x; i < cp; i += blockDim.x) {
      perm[e * T_TOK + i] = 0;
      pw[e * T_TOK + i]   = 0.f;
    }
  }
}

// ---------------- atomic-free combine: out[t] = sum_s w_s * (y0[row_s] + y1[row_s]) ----------------
__global__ __launch_bounds__(256) void combine_kernel(
    const float* __restrict__ y0, const float* __restrict__ y1,
    const int* __restrict__ offs, const int* __restrict__ tok2slot,
    const float* __restrict__ tokw, float* __restrict__ out)
{
  const int t = blockIdx.x;
  const int d = threadIdx.x * 4;
  const int s0 = tok2slot[2 * t + 0];
  const int s1 = tok2slot[2 * t + 1];
  const float w0 = tokw[2 * t + 0];
  const float w1 = tokw[2 * t + 1];
  const size_t r0 = (size_t)(offs[s0 >> 16] + (s0 & 0xffff)) * DM + d;
  const size_t r1 = (size_t)(offs[s1 >> 16] + (s1 & 0xffff)) * DM + d;
  float4 a0 = *(const float4*)(y0 + r0);
  float4 b0 = *(const float4*)(y1 + r0);
  float4 a1 = *(const float4*)(y0 + r1);
  float4 b1 = *(const float4*)(y1 + r1);
  float4 o;
  o.x = w0 * (a0.x + b0.x) + w1 * (a1.x + b1.x);
  o.y = w0 * (a0.y + b0.y) + w1 * (a1.y + b1.y);
  o.z = w0 * (a0.z + b0.z) + w1 * (a1.z + b1.z);
  o.w = w0 * (a0.w + b0.w) + w1 * (a1.w + b1.w);
  *(float4*)(out + (size_t)t * DM + d) = o;
}

// ======== v5 GEMM (FROZEN): BK=64, tile-packed operands, depth-1 reg prefetch ========
// PHASE 1: H = relu(X_e * W1 + b1), H stored TILE-PACKED [rb][kt][128][64]
// PHASE 2: y[ks][row] = H_e * W2 (+ b2 if ks==0) -- PLAIN f32 stores, no atomics
template<int PHASE, int KTOT, int NCOLS, int KSPLIT>
__global__ __launch_bounds__(256, 3) void moe_gemm5(
    const unsigned short* __restrict__ Asrc,
    const unsigned short* __restrict__ Bt,
    const float* __restrict__ bias,
    const int* __restrict__ cntpad, const int* __restrict__ offs,
    const int* __restrict__ perm,
    unsigned short* __restrict__ Hout, float* __restrict__ yout)
{
  const int e  = blockIdx.z;
  const int mt = blockIdx.y;
  const int nt = blockIdx.x / KSPLIT;
  const int ks = blockIdx.x % KSPLIT;
  const int cp = cntpad[e];
  if (mt * BM >= cp) return;
  const int tid = threadIdx.x;
  const int oe  = offs[e];

  __shared__ unsigned short As[BM * LDA2];
  __shared__ unsigned short Bs[BN * LDA2];

  const int am = tid >> 1;
  const int ak = (tid & 1) * 32;
  const int kb0 = ks * (KTOT / KSPLIT);
  const int KITERS = (KTOT / KSPLIT) / BK;

  const unsigned short* Ap;
  size_t APITCH;
  if (PHASE == 1) {
    int token = perm[e * T_TOK + mt * BM + am];
    Ap = Asrc + (size_t)token * KTOT + kb0 + ak;
    APITCH = BK;
  } else {
    const size_t rb = (size_t)(oe >> 7) + mt;        // H row-block (oe is 128-multiple)
    Ap = Asrc + (((rb * (KTOT / 64) + (kb0 >> 6)) * 128 + am) * 64) + ak;
    APITCH = (size_t)128 * 64;
  }
  const unsigned short* Bp =
      Bt + ((((size_t)e * (NCOLS / 128) + nt) * (KTOT / 64) + (kb0 >> 6)) * 128 + am) * 64 + ak;

  const int wid  = tid >> 6;
  const int lane = tid & 63;
  const int wm   = (wid & 1) * 64;
  const int wn   = (wid >> 1) * 64;
  const int lrow = lane & 15;
  const int lk   = (lane >> 4) * 8;

  f32x4 acc[4][4];
#pragma unroll
  for (int i = 0; i < 4; i++)
#pragma unroll
    for (int j = 0; j < 4; j++) acc[i][j] = (f32x4){0.f, 0.f, 0.f, 0.f};

  uint4 pa0, pa1, pa2, pa3, pb0, pb1, pb2, pb3;
  auto LOADT = [&](int kt) {
    const unsigned short* a = Ap + (size_t)kt * APITCH;
    const unsigned short* b = Bp + (size_t)kt * (128 * 64);
    pa0 = *(const uint4*)(a);      pa1 = *(const uint4*)(a + 8);
    pa2 = *(const uint4*)(a + 16); pa3 = *(const uint4*)(a + 24);
    pb0 = *(const uint4*)(b);      pb1 = *(const uint4*)(b + 8);
    pb2 = *(const uint4*)(b + 16); pb3 = *(const uint4*)(b + 24);
  };
  auto STORET = [&]() {
    unsigned short* as = &As[am * LDA2 + ak];
    unsigned short* bs = &Bs[am * LDA2 + ak];
    *(uint4*)(as)      = pa0; *(uint4*)(as + 8)  = pa1;
    *(uint4*)(as + 16) = pa2; *(uint4*)(as + 24) = pa3;
    *(uint4*)(bs)      = pb0; *(uint4*)(bs + 8)  = pb1;
    *(uint4*)(bs + 16) = pb2; *(uint4*)(bs + 24) = pb3;
  };

  LOADT(0);
  STORET();
  for (int kt = 0; kt < KITERS; kt++) {
    __syncthreads();
    if (kt + 1 < KITERS) LOADT(kt + 1);
#pragma unroll
    for (int ksb = 0; ksb < 2; ksb++) {
      bf16x8 af[4], bfr[4];
#pragma unroll
      for (int i = 0; i < 4; i++)
        af[i]  = *(const bf16x8*)&As[(wm + i * 16 + lrow) * LDA2 + ksb * 32 + lk];
#pragma unroll
      for (int j = 0; j < 4; j++)
        bfr[j] = *(const bf16x8*)&Bs[(wn + j * 16 + lrow) * LDA2 + ksb * 32 + lk];
#pragma unroll
      for (int i = 0; i < 4; i++)
#pragma unroll
        for (int j = 0; j < 4; j++)
          acc[i][j] = __builtin_amdgcn_mfma_f32_16x16x32_bf16(af[i], bfr[j], acc[i][j], 0, 0, 0);
    }
    __syncthreads();
    if (kt + 1 < KITERS) STORET();
  }

  // epilogue: C/D layout col=lane&15, row=(lane>>4)*4+reg
  const int crow = (lane >> 4) * 4;
  const int ccol = lane & 15;
  const size_t rbh = (size_t)(oe >> 7) + mt;
  float* yp = yout + (size_t)ks * ((size_t)YROWS * NCOLS);   // ks-partial buffer
#pragma unroll
  for (int j = 0; j < 4; j++) {
    const int gn = nt * BN + wn + j * 16 + ccol;
    const float bv = bias[e * NCOLS + gn];
#pragma unroll
    for (int i = 0; i < 4; i++) {
#pragma unroll
      for (int r = 0; r < 4; r++) {
        const int lm = wm + i * 16 + crow + r;
        float v = acc[i][j][r];
        if (PHASE == 1) {
          v += bv;
          v = v > 0.f ? v : 0.f;
          Hout[(((rbh * (NCOLS / 64) + (gn >> 6)) * 128 + lm) * 64) + (gn & 63)] = f2bf(v);
        } else {
          if (ks == 0) v += bv;
          yp[(size_t)(oe + mt * BM + lm) * NCOLS + gn] = v;   // plain store
        }
      }
    }
  }
}

// ======== v1 GEMM (fallback, f32 weights in-flight, row-major H, atomics) ========
template<int PHASE, int KTOT, int NCOLS, int KSPLIT>
__global__ __launch_bounds__(256) void moe_gemm_v1(
    const unsigned short* __restrict__ Asrc,
    const float* __restrict__ Wbase,
    const float* __restrict__ bias,
    const int* __restrict__ cntpad, const int* __restrict__ offs,
    const int* __restrict__ perm, const float* __restrict__ pw,
    unsigned short* __restrict__ Hout, float* __restrict__ out)
{
  const int e  = blockIdx.z;
  const int mt = blockIdx.y;
  const int nt = blockIdx.x / KSPLIT;
  const int ks = blockIdx.x % KSPLIT;
  const int cp = cntpad[e];
  if (mt * BM >= cp) return;
  const int tid = threadIdx.x;
  const int oe  = offs[e];

  __shared__ unsigned short As[BM * LDAV1];
  __shared__ unsigned short Bs[BN * LDAV1];

  const int am = tid >> 1;
  const int ak = (tid & 1) * 16;
  size_t arow_off;
  if (PHASE == 1) {
    int token = perm[e * T_TOK + mt * BM + am];
    arow_off = (size_t)token * KTOT;
  } else {
    arow_off = (size_t)(oe + mt * BM + am) * (size_t)KTOT;
  }
  const int bn  = tid & 127;
  const int bk0 = (tid >> 7) * 16;
  const float* Wexp = Wbase + (size_t)e * KTOT * NCOLS + (size_t)nt * BN;
  const int kbase0 = ks * (KTOT / KSPLIT);
  const int KITERS = (KTOT / KSPLIT) / 32;
  const int wid  = tid >> 6;
  const int lane = tid & 63;
  const int wm   = (wid & 1) * 64;
  const int wn   = (wid >> 1) * 64;
  const int lrow = lane & 15;
  const int lk   = (lane >> 4) * 8;

  f32x4 acc[4][4];
#pragma unroll
  for (int i = 0; i < 4; i++)
#pragma unroll
    for (int j = 0; j < 4; j++) acc[i][j] = (f32x4){0.f, 0.f, 0.f, 0.f};

  for (int kt = 0; kt < KITERS; kt++) {
    const int kb = kbase0 + kt * 32;
    {
      const unsigned short* src = Asrc + arow_off + kb + ak;
      uint4 v0 = *(const uint4*)(src);
      uint4 v1 = *(const uint4*)(src + 8);
      *(uint4*)&As[am * LDAV1 + ak]     = v0;
      *(uint4*)&As[am * LDAV1 + ak + 8] = v1;
    }
#pragma unroll
    for (int t2 = 0; t2 < 2; t2++) {
      const int kk = bk0 + t2 * 8;
      const float* wp = Wexp + (size_t)(kb + kk) * NCOLS + bn;
      ushort8 tv;
#pragma unroll
      for (int j = 0; j < 8; j++) tv[j] = f2bf(wp[(size_t)j * NCOLS]);
      *(ushort8*)&Bs[bn * LDAV1 + kk] = tv;
    }
    __syncthreads();
    bf16x8 af[4], bfr[4];
#pragma unroll
    for (int i = 0; i < 4; i++) af[i]  = *(const bf16x8*)&As[(wm + i * 16 + lrow) * LDAV1 + lk];
#pragma unroll
    for (int j = 0; j < 4; j++) bfr[j] = *(const bf16x8*)&Bs[(wn + j * 16 + lrow) * LDAV1 + lk];
#pragma unroll
    for (int i = 0; i < 4; i++)
#pragma unroll
      for (int j = 0; j < 4; j++)
        acc[i][j] = __builtin_amdgcn_mfma_f32_16x16x32_bf16(af[i], bfr[j], acc[i][j], 0, 0, 0);
    __syncthreads();
  }

  const int crow = (lane >> 4) * 4;
  const int ccol = lane & 15;
#pragma unroll
  for (int j = 0; j < 4; j++) {
    const int gn = nt * BN + wn + j * 16 + ccol;
    const float bv = bias[e * NCOLS + gn];
#pragma unroll
    for (int i = 0; i < 4; i++) {
#pragma unroll
      for (int r = 0; r < 4; r++) {
        const int lm = wm + i * 16 + crow + r;
        float v = acc[i][j][r];
        if (PHASE == 1) {
          v += bv;
          v = v > 0.f ? v : 0.f;
          Hout[(size_t)(oe + mt * BM + lm) * NCOLS + gn] = f2bf(v);
        } else {
          if (ks == 0) v += bv;
          const int li    = e * T_TOK + mt * BM + lm;
          const int token = perm[li];
          const float w   = pw[li];
          atomicAdd(&out[(size_t)token * NCOLS + gn], w * v);
        }
      }
    }
  }
}

extern "C" void kernel_launch(void* const* d_in, const int* in_sizes, int n_in,
                              void* d_out, int out_size, void* d_ws, size_t ws_size,
                              hipStream_t stream) {
  const float* x  = (const float*)d_in[0];
  const float* wg = (const float*)d_in[1];
  const float* bg = (const float*)d_in[2];
  const float* w1 = (const float*)d_in[3];
  const float* b1 = (const float*)d_in[4];
  const float* w2 = (const float*)d_in[5];
  const float* b2 = (const float*)d_in[6];
  float* out = (float*)d_out;

  // ---- workspace layout ----
  const size_t XB_BYTES   = (size_t)T_TOK * DM * 2;          // 4 MB
  const size_t PERM_BYTES = (size_t)NE * T_TOK * 4;          // 64 KB
  const size_t PW_BYTES   = (size_t)NE * T_TOK * 4;          // 64 KB
  const size_t TOK_BYTES  = (size_t)T_TOK * 2 * 4;           // 16 KB (x2)
  const size_t H_BYTES    = (size_t)(2 * T_TOK + NE * BM) * DF * 2;  // 40 MB (packed layout)
  const size_t W1T_BYTES  = (size_t)NE * DF * DM * 2;        // 64 MB
  const size_t W2T_BYTES  = (size_t)NE * DM * DF * 2;        // 64 MB

  char* wsp = (char*)d_ws;
  size_t off = 0;
  unsigned short* xb = (unsigned short*)(wsp + off); off += XB_BYTES;
  int*   cnt    = (int*)(wsp + off); off += 256;             // cnt/cntpad/offs packed
  int*   cntpad = cnt + 8;
  int*   offs   = cnt + 16;
  int*   perm   = (int*)(wsp + off);   off += PERM_BYTES;
  float* pwt    = (float*)(wsp + off); off += PW_BYTES;
  int*   tok2slot = (int*)(wsp + off);   off += TOK_BYTES;
  float* tokw     = (float*)(wsp + off); off += TOK_BYTES;
  unsigned short* H   = (unsigned short*)(wsp + off); off += H_BYTES;
  unsigned short* w1t = (unsigned short*)(wsp + off); off += W1T_BYTES;
  unsigned short* w2t = (unsigned short*)(wsp + off); off += W2T_BYTES;
  const size_t REQUIRED = off;

  // y partials alias w1t (dead after phase 1): 2 buffers x YROWS x DM f32 = 40 MB <= 64 MB
  float* y = (float*)w1t;

  hipMemsetAsync(cnt, 0, 256, stream);

  gating_kernel<<<T_TOK / 4, 256, 0, stream>>>(x, wg, bg, cnt, perm, pwt, tok2slot, tokw);
  pad_scan_kernel<<<1, 256, 0, stream>>>(cnt, cntpad, offs, perm, pwt);

  if (ws_size >= REQUIRED) {
    // weight convert+pack (32k tiles, 8 blocks/CU) + x convert, one launch
    prep_all<<<17408, 256, 0, stream>>>(x, xb, w1, w2, w1t, w2t);

    moe_gemm5<1, DM, DF, 1><<<dim3(DF / BN, T_TOK / BM, NE), 256, 0, stream>>>(
        xb, w1t, b1, cntpad, offs, perm, H, nullptr);
    // phase 2: plain stores into y[ks] (aliases w1t, which is dead now)
    moe_gemm5<2, DF, DM, 2><<<dim3((DM / BN) * 2, T_TOK / BM, NE), 256, 0, stream>>>(
        H, w2t, b2, cntpad, offs, perm, nullptr, y);
    combine_kernel<<<T_TOK, 256, 0, stream>>>(
        y, y + (size_t)YROWS * DM, offs, tok2slot, tokw, out);
  } else {
    // fallback: v1 path (needs only ~46 MB of ws), row-major H, atomic combine
    hipMemsetAsync(d_out, 0, (size_t)T_TOK * DM * 4, stream);
    convert_x_kernel<<<(T_TOK * DM / 8) / 256, 256, 0, stream>>>(x, xb);
    moe_gemm_v1<1, DM, DF, 1><<<dim3(DF / BN, T_TOK / BM, NE), 256, 0, stream>>>(
        xb, w1, b1, cntpad, offs, perm, pwt, H, nullptr);
    moe_gemm_v1<2, DF, DM, 4><<<dim3((DM / BN) * 4, T_TOK / BM, NE), 256, 0, stream>>>(
        H, w2, b2, cntpad, offs, perm, pwt, nullptr, out);
  }
}